// Round 4
// baseline (83.143 us; speedup 1.0000x reference)
//
#include <hip/hip_runtime.h>

typedef unsigned short u16;
typedef unsigned int u32;
typedef __attribute__((ext_vector_type(8))) __bf16 bf16x8;
typedef __attribute__((ext_vector_type(4))) float f32x4;
typedef __attribute__((ext_vector_type(16))) float f32x16;
typedef __attribute__((ext_vector_type(4))) u32 u32x4;

#if __has_builtin(__builtin_amdgcn_exp2f)
#define EXP2F(x) __builtin_amdgcn_exp2f(x)
#else
#define EXP2F(x) exp2f(x)
#endif

// 0.125 (1/sqrt(64)) * log2(e): folded into Wq/bq so scores are in exp2 domain
#define SC_Q 0.18033688011112042f

static __device__ __forceinline__ u16 f2bf(float f) {
  unsigned u = __builtin_bit_cast(unsigned, f);
  u += 0x7fffu + ((u >> 16) & 1u);
  return (u16)(u >> 16);
}

static __device__ __forceinline__ f32x4 mfma16(bf16x8 a, bf16x8 b, f32x4 c) {
  return __builtin_amdgcn_mfma_f32_16x16x32_bf16(a, b, c, 0, 0, 0);
}
static __device__ __forceinline__ f32x16 mfma32(bf16x8 a, bf16x8 b, f32x16 c) {
  return __builtin_amdgcn_mfma_f32_32x32x16_bf16(a, b, c, 0, 0, 0);
}

static __device__ __forceinline__ u32 cvtpk(float lo, float hi_) {
  u32 r;
  asm("v_cvt_pk_bf16_f32 %0, %1, %2" : "=v"(r) : "v"(lo), "v"(hi_));
  return r;
}

static __device__ __forceinline__ void barrier_raw() {
  asm volatile("" ::: "memory");
  __builtin_amdgcn_s_barrier();
  asm volatile("" ::: "memory");
}

static __device__ __forceinline__ void gload_lds16(const u16* g, u16* l) {
  __builtin_amdgcn_global_load_lds((const __attribute__((address_space(1))) u32*)g,
                                   (__attribute__((address_space(3))) u32*)l, 16, 0, 0);
}

// ---------------- pack kernels ----------------
__global__ void pack_x_kernel(const float* __restrict__ x, u16* __restrict__ xb, int n) {
  int idx = blockIdx.x * 256 + threadIdx.x;
  if (idx < n) xb[idx] = f2bf(x[idx]);
}

// BTqkv[n][d], n = t*512 + h*64 + e  (t: 0=q,1=k,2=v); Wq scaled by SC_Q
__global__ void pack_wqkv_kernel(const float* __restrict__ Wq, const float* __restrict__ Wk,
                                 const float* __restrict__ Wv, u16* __restrict__ BT) {
  int idx = blockIdx.x * 256 + threadIdx.x;
  if (idx >= 1536 * 512) return;
  int n = idx >> 9, d = idx & 511;
  int t = n >> 9, rem = n & 511;
  int h = rem >> 6, e = rem & 63;
  const float* W = (t == 0) ? Wq : ((t == 1) ? Wk : Wv);
  float sc = (t == 0) ? SC_Q : 1.0f;
  BT[idx] = f2bf(W[((size_t)h * 512 + d) * 64 + e] * sc);
}

__global__ void pack_bias_kernel(const float* __restrict__ bq, const float* __restrict__ bk,
                                 const float* __restrict__ bv, float* __restrict__ bqkv) {
  int idx = blockIdx.x * 256 + threadIdx.x;
  if (idx >= 1536) return;
  int t = idx >> 9, rem = idx & 511;
  float v = (t == 0 ? bq : (t == 1 ? bk : bv))[rem];
  bqkv[idx] = v * (t == 0 ? SC_Q : 1.0f);
}

// BTo[n][d] = Wo[d][n]
__global__ void pack_wo_kernel(const float* __restrict__ Wo, u16* __restrict__ BTo) {
  int idx = blockIdx.x * 256 + threadIdx.x;
  if (idx >= 512 * 512) return;
  int n = idx >> 9, d = idx & 511;
  BTo[idx] = f2bf(Wo[(size_t)d * 512 + n]);
}

// V [4096][1536 @1024+h*64] -> Vt [(b*8+h)*64+e][1024]
__global__ __launch_bounds__(256) void transpose_v_kernel(const u16* __restrict__ QKV,
                                                          u16* __restrict__ Vt) {
  __shared__ u16 t[64][72];
  const int tid = threadIdx.x;
  const int s0 = blockIdx.x * 64;
  const int bh = blockIdx.y;
  const int h = bh & 7, b = bh >> 3;
#pragma unroll
  for (int c2 = 0; c2 < 2; ++c2) {
    int slot = c2 * 256 + tid;
    int sr = slot >> 3, e8 = (slot & 7) * 8;
    uint4 vv = *reinterpret_cast<const uint4*>(
        QKV + (size_t)(b * 1024 + s0 + sr) * 1536 + 1024 + h * 64 + e8);
    *reinterpret_cast<uint4*>(&t[sr][e8]) = vv;
  }
  __syncthreads();
#pragma unroll
  for (int c2 = 0; c2 < 2; ++c2) {
    int slot = c2 * 256 + tid;
    int er = slot >> 3, j8 = (slot & 7) * 8;
    u16 tmp[8];
#pragma unroll
    for (int k = 0; k < 8; ++k) tmp[k] = t[j8 + k][er];
    *reinterpret_cast<uint4*>(Vt + (size_t)(bh * 64 + er) * 1024 + s0 + j8) =
        *reinterpret_cast<const uint4*>(tmp);
  }
}

// ---------------- GEMM: C[M][N] = A[M][K] @ BT[N][K]^T + bias ----------------
template <int OUT_BF16>
__global__ __launch_bounds__(256) void gemm_bt_kernel(
    const u16* __restrict__ A, const u16* __restrict__ BT, const float* __restrict__ bias,
    u16* __restrict__ Cb, float* __restrict__ Cf, int M, int N, int K) {
  __shared__ __align__(16) u16 Alds[64][40];
  __shared__ __align__(16) u16 Blds[64][40];
  const int tid = threadIdx.x;
  const int w = tid >> 6, lane = tid & 63, g = lane >> 4, i = lane & 15;
  const int m0 = blockIdx.y * 64, n0 = blockIdx.x * 64;
  const int wr = (w >> 1) * 32, wc = (w & 1) * 32;
  f32x4 acc[2][2];
#pragma unroll
  for (int a = 0; a < 2; ++a)
#pragma unroll
    for (int b = 0; b < 2; ++b) acc[a][b] = f32x4{0.f, 0.f, 0.f, 0.f};

  const int srow = tid >> 2, sc = (tid & 3) * 8;
  const u16* Aptr = A + (size_t)(m0 + srow) * K + sc;
  const u16* Bptr = BT + (size_t)(n0 + srow) * K + sc;

  for (int k0 = 0; k0 < K; k0 += 32) {
    __syncthreads();
    *reinterpret_cast<uint4*>(&Alds[srow][sc]) = *reinterpret_cast<const uint4*>(Aptr + k0);
    *reinterpret_cast<uint4*>(&Blds[srow][sc]) = *reinterpret_cast<const uint4*>(Bptr + k0);
    __syncthreads();
    bf16x8 af[2], bfr[2];
#pragma unroll
    for (int mf = 0; mf < 2; ++mf)
      af[mf] = *reinterpret_cast<const bf16x8*>(&Alds[wr + mf * 16 + i][8 * g]);
#pragma unroll
    for (int nf = 0; nf < 2; ++nf)
      bfr[nf] = *reinterpret_cast<const bf16x8*>(&Blds[wc + nf * 16 + i][8 * g]);
#pragma unroll
    for (int mf = 0; mf < 2; ++mf)
#pragma unroll
      for (int nf = 0; nf < 2; ++nf) acc[mf][nf] = mfma16(af[mf], bfr[nf], acc[mf][nf]);
  }

#pragma unroll
  for (int mf = 0; mf < 2; ++mf) {
#pragma unroll
    for (int nf = 0; nf < 2; ++nf) {
#pragma unroll
      for (int r = 0; r < 4; ++r) {
        int row = m0 + wr + mf * 16 + 4 * g + r;
        int col = n0 + wc + nf * 16 + i;
        float v = acc[mf][nf][r] + bias[col];
        if (OUT_BF16)
          Cb[(size_t)row * N + col] = f2bf(v);
        else
          Cf[(size_t)row * N + col] = v;
      }
    }
  }
}

// ---------------- attention v3: 32x32 swapped-QK, 4-way KV split ----------------
// grid (h=8, qt=8, b*4+s=16); 256 thr = 4 waves, wave w owns q rows [q0w, q0w+32)
// each block processes keys [s*256, s*256+256), writes partial O (f32) + (m,l)
__global__ __launch_bounds__(256) void attn3_kernel(const u16* __restrict__ QKV,
                                                    const u16* __restrict__ Vt,
                                                    float* __restrict__ Opart,
                                                    float* __restrict__ mlpart) {
  __shared__ __align__(16) u16 Kl[2][4096];  // [64 j][8 eb-blocks of 8] XOR-swizzled
  __shared__ __align__(16) u16 Vl[2][4096];  // [64 e][8 jb-blocks of 8] XOR-swizzled

  const int tid = threadIdx.x;
  const int w = tid >> 6, lane = tid & 63;
  const int col = lane & 31, hi = lane >> 5;
  const int h = blockIdx.x;                 // XCD = flat%8 = h: per-XCD K/V locality
  const int zz = blockIdx.z;
  const int b = zz >> 2, s = zz & 3;
  const int bh = b * 8 + h;
  const int q0w = blockIdx.y * 128 + w * 32;
  const int kvlo = s * 256;
  const int hm = (h < 4) ? h : 4;
  const int band = 1 << hm;
  const int modm = (2 << hm) - 1;
  const int qrow = q0w + col;

  // Q fragments (B-operand): lane holds Q[qrow][16*et + 8*hi + b]
  bf16x8 qf[4];
  const size_t qoff = (size_t)(b * 1024 + qrow) * 1536 + h * 64 + 8 * hi;
#pragma unroll
  for (int et = 0; et < 4; ++et)
    qf[et] = *reinterpret_cast<const bf16x8*>(QKV + qoff + 16 * et);

  // dilation bias per C-reg r (invariant across kv tiles: 64 % 2^(hm+1) == 0)
  float bias[16];
#pragma unroll
  for (int r = 0; r < 16; ++r) {
    int c = (r & 3) + 8 * (r >> 2) + 4 * hi;
    bias[r] = (((qrow - c) & modm) == 0) ? 0.f : -1e30f;
  }

  f32x16 accO0 = {}, accO1 = {};
  float m_run = -1e30f, l_run = 0.f;

  // staging: slot -> linear LDS (slot*16B); global source pre-swizzled (rule #21)
  const int slot0 = tid, slot1 = tid + 256;
  const int kj0 = slot0 >> 3, keb0 = (slot0 & 7) ^ (kj0 & 7);
  const int kj1 = slot1 >> 3, keb1 = (slot1 & 7) ^ (kj1 & 7);
  const u16* kg0 = QKV + (size_t)(b * 1024 + kj0) * 1536 + 512 + h * 64 + keb0 * 8;
  const u16* kg1 = QKV + (size_t)(b * 1024 + kj1) * 1536 + 512 + h * 64 + keb1 * 8;
  const u16* vg0 = Vt + (size_t)(bh * 64 + kj0) * 1024 + keb0 * 8;  // e=kj0, jb=keb0
  const u16* vg1 = Vt + (size_t)(bh * 64 + kj1) * 1024 + keb1 * 8;

#define STAGE(bi, kv0)                                                  \
  do {                                                                  \
    gload_lds16(kg0 + (size_t)(kv0) * 1536, &Kl[bi][slot0 * 8]);        \
    gload_lds16(kg1 + (size_t)(kv0) * 1536, &Kl[bi][slot1 * 8]);        \
    gload_lds16(vg0 + (kv0), &Vl[bi][slot0 * 8]);                       \
    gload_lds16(vg1 + (kv0), &Vl[bi][slot1 * 8]);                       \
  } while (0)

  STAGE(0, kvlo);
  int buf = 0;

  for (int t = 0; t < 4; ++t) {
    const int kv0 = kvlo + t * 64;
    if (t < 3) {
      STAGE(buf ^ 1, kv0 + 64);
      asm volatile("s_waitcnt vmcnt(4)" ::: "memory");
    } else {
      asm volatile("s_waitcnt vmcnt(0)" ::: "memory");
    }
    barrier_raw();

    const u16* Kb = Kl[buf];
    const u16* Vb = Vl[buf];

    // QK^T swapped: s = mfma(K, Q); D[m=j][n=q], lane: n=col, m=crow(r,hi)
    f32x16 s0 = {}, s1 = {};
#pragma unroll
    for (int et = 0; et < 4; ++et) {
      const int sw = ((2 * et + hi) ^ (col & 7)) << 3;
      bf16x8 kf0 = *reinterpret_cast<const bf16x8*>(&Kb[col * 64 + sw]);
      bf16x8 kf1 = *reinterpret_cast<const bf16x8*>(&Kb[(col + 32) * 64 + sw]);
      s0 = mfma32(kf0, qf[et], s0);
      s1 = mfma32(kf1, qf[et], s1);
    }

    // mask (scores already in exp2 domain)
    float p[32];
    const int dq = qrow - kv0;
    const bool near = (q0w <= kv0 + 63 + band) && (kv0 <= q0w + 31 + band);
    if (near) {
#pragma unroll
      for (int r = 0; r < 16; ++r) {
        const int c = (r & 3) + 8 * (r >> 2) + 4 * hi;
        int d0 = dq - c, d1 = d0 - 32;
        d0 = d0 < 0 ? -d0 : d0;
        d1 = d1 < 0 ? -d1 : d1;
        p[r] = (d0 <= band) ? s0[r] : s0[r] + bias[r];
        p[r + 16] = (d1 <= band) ? s1[r] : s1[r] + bias[r];
      }
    } else {
#pragma unroll
      for (int r = 0; r < 16; ++r) {
        p[r] = s0[r] + bias[r];
        p[r + 16] = s1[r] + bias[r];
      }
    }

    // row max: tree reduce (5 dep levels) + lane^32 combine
    float tr[16];
#pragma unroll
    for (int j = 0; j < 16; ++j) tr[j] = fmaxf(p[j], p[j + 16]);
#pragma unroll
    for (int st = 8; st >= 1; st >>= 1)
#pragma unroll
      for (int j = 0; j < st; ++j) tr[j] = fmaxf(tr[j], tr[j + st]);
    float mu = fmaxf(tr[0], __shfl_xor(tr[0], 32));

    // defer-max (T13): rescale only on real growth
    if (__any(mu > m_run + 8.f)) {
      float mn = fmaxf(m_run, mu);
      float corr = EXP2F(m_run - mn);
      m_run = mn;
      l_run *= corr;
#pragma unroll
      for (int j = 0; j < 16; ++j) {
        accO0[j] *= corr;
        accO1[j] *= corr;
      }
    }

#pragma unroll
    for (int j = 0; j < 32; ++j) p[j] = EXP2F(p[j] - m_run);
    float ts[16];
#pragma unroll
    for (int j = 0; j < 16; ++j) ts[j] = p[j] + p[j + 16];
#pragma unroll
    for (int st = 8; st >= 1; st >>= 1)
#pragma unroll
      for (int j = 0; j < st; ++j) ts[j] += ts[j + st];
    l_run += ts[0] + __shfl_xor(ts[0], 32);

    // P -> A-frag in-register (cvt_pk + shfl_xor lane^32 exchange), then PV
#pragma unroll
    for (int kt = 0; kt < 4; ++kt) {
      const float* pp = (kt < 2) ? p : p + 16;  // mt = kt>>1 (compile-time)
      const int R = (kt & 1) * 8;
      u32 A0 = cvtpk(pp[R + 0], pp[R + 1]);
      u32 A1 = cvtpk(pp[R + 2], pp[R + 3]);
      u32 B0 = cvtpk(pp[R + 4], pp[R + 5]);
      u32 B1 = cvtpk(pp[R + 6], pp[R + 7]);
      u32 xA0 = __shfl_xor(A0, 32), xA1 = __shfl_xor(A1, 32);
      u32 xB0 = __shfl_xor(B0, 32), xB1 = __shfl_xor(B1, 32);
      // hi=0 lane supplies k=0..7 -> keys 16kt+0..7  = {own A-words, partner A-words}
      // hi=1 lane supplies k=8..15 -> keys 16kt+8..15 = {partner B-words, own B-words}
      u32 w0 = hi ? xB0 : A0;
      u32 w1 = hi ? xB1 : A1;
      u32 w2 = hi ? B0 : xA0;
      u32 w3 = hi ? B1 : xA1;
      u32x4 pu = {w0, w1, w2, w3};
      bf16x8 paf = __builtin_bit_cast(bf16x8, pu);
      const int jb = 2 * kt + hi;
      {
        const int erow = col;  // nt = 0
        bf16x8 vf = *reinterpret_cast<const bf16x8*>(&Vb[erow * 64 + ((jb ^ (erow & 7)) << 3)]);
        accO0 = mfma32(paf, vf, accO0);
      }
      {
        const int erow = 32 + col;  // nt = 1
        bf16x8 vf = *reinterpret_cast<const bf16x8*>(&Vb[erow * 64 + ((jb ^ (erow & 7)) << 3)]);
        accO1 = mfma32(paf, vf, accO1);
      }
    }

    barrier_raw();
    buf ^= 1;
  }
#undef STAGE

  // epilogue: write unnormalized partial O (f32) + per-row (m,l)
  const size_t obase = (size_t)(s * 32 + bh) * 1024 + q0w;
  if (lane < 32) {
    float2 ml2 = {m_run, l_run};
    *reinterpret_cast<float2*>(&mlpart[(obase + col) * 2]) = ml2;
  }
#pragma unroll
  for (int r = 0; r < 16; ++r) {
    const int c = (r & 3) + 8 * (r >> 2) + 4 * hi;
    float* orow = Opart + (obase + c) * 64;
    orow[col] = accO0[r];
    orow[32 + col] = accO1[r];
  }
}

// ---------------- combine: merge 4 KV-split partials, write bf16 concat ----------------
__global__ __launch_bounds__(256) void attn_combine_kernel(const float* __restrict__ Opart,
                                                           const float* __restrict__ mlpart,
                                                           u16* __restrict__ Cc) {
  const int gid = blockIdx.x * 256 + threadIdx.x;  // 32768 rows * 16 e-quads
  const int rg = gid >> 4;                         // bh*1024 + qrow
  const int e0 = (gid & 15) * 4;
  float m[4], l[4];
#pragma unroll
  for (int s2 = 0; s2 < 4; ++s2) {
    float2 ml2 = *reinterpret_cast<const float2*>(&mlpart[((size_t)s2 * 32768 + rg) * 2]);
    m[s2] = ml2.x;
    l[s2] = ml2.y;
  }
  const float M = fmaxf(fmaxf(m[0], m[1]), fmaxf(m[2], m[3]));
  float L = 0.f, wsc[4];
#pragma unroll
  for (int s2 = 0; s2 < 4; ++s2) {
    wsc[s2] = EXP2F(m[s2] - M);
    L += l[s2] * wsc[s2];
  }
  float4 o = {0.f, 0.f, 0.f, 0.f};
#pragma unroll
  for (int s2 = 0; s2 < 4; ++s2) {
    float4 op = *reinterpret_cast<const float4*>(&Opart[((size_t)s2 * 32768 + rg) * 64 + e0]);
    o.x += op.x * wsc[s2];
    o.y += op.y * wsc[s2];
    o.z += op.z * wsc[s2];
    o.w += op.w * wsc[s2];
  }
  const float inv = 1.0f / L;
  const int bh = rg >> 10, qr = rg & 1023;
  u16 ob[4] = {f2bf(o.x * inv), f2bf(o.y * inv), f2bf(o.z * inv), f2bf(o.w * inv)};
  *reinterpret_cast<uint2*>(&Cc[(size_t)((bh >> 3) * 1024 + qr) * 512 + (bh & 7) * 64 + e0]) =
      *reinterpret_cast<const uint2*>(ob);
}

// ---------------- launch ----------------
extern "C" void kernel_launch(void* const* d_in, const int* in_sizes, int n_in,
                              void* d_out, int out_size, void* d_ws, size_t ws_size,
                              hipStream_t stream) {
  const float* x = (const float*)d_in[0];
  const float* Wq = (const float*)d_in[1];
  const float* bq = (const float*)d_in[2];
  const float* Wk = (const float*)d_in[3];
  const float* bk = (const float*)d_in[4];
  const float* Wv = (const float*)d_in[5];
  const float* bv = (const float*)d_in[6];
  const float* Wo = (const float*)d_in[7];
  const float* bo = (const float*)d_in[8];
  float* out = (float*)d_out;

  char* ws = (char*)d_ws;
  u16* xb = (u16*)(ws);                     // 4 MB   [4096][512]
  u16* BTqkv = (u16*)(ws + (4u << 20));     // 1.5 MB [1536][512]
  u16* BTo = (u16*)(ws + (6u << 20));       // 0.5 MB [512][512]
  float* bqkv = (float*)(ws + (7u << 20));  // 6 KB
  u16* QKV = (u16*)(ws + (8u << 20));       // 12.6 MB [4096][1536]
  u16* Cc = (u16*)(ws + (21u << 20));       // 4 MB   [4096][512]
  u16* Vt = (u16*)(ws + (25u << 20));       // 4 MB   [32*64][1024]
  float* Opart = (float*)(ws + (32u << 20));   // 32 MB [4 splits][32 bh][1024][64]
  float* mlpart = (float*)(ws + (64u << 20));  // 1 MB  [4 splits][32 bh][1024][2]

  const int NX = 4096 * 512;
  pack_x_kernel<<<(NX + 255) / 256, 256, 0, stream>>>(x, xb, NX);
  pack_wqkv_kernel<<<(1536 * 512 + 255) / 256, 256, 0, stream>>>(Wq, Wk, Wv, BTqkv);
  pack_bias_kernel<<<6, 256, 0, stream>>>(bq, bk, bv, bqkv);
  pack_wo_kernel<<<(512 * 512 + 255) / 256, 256, 0, stream>>>(Wo, BTo);

  // QKV projection: [4096,512] @ [512,1536] -> bf16 QKV (Wq pre-scaled)
  gemm_bt_kernel<1><<<dim3(1536 / 64, 4096 / 64), 256, 0, stream>>>(
      xb, BTqkv, bqkv, QKV, nullptr, 4096, 1536, 512);

  // V -> Vt
  transpose_v_kernel<<<dim3(16, 32), 256, 0, stream>>>(QKV, Vt);

  // attention: 4-way KV split (grid x=h for XCD L2 locality)
  attn3_kernel<<<dim3(8, 8, 16), 256, 0, stream>>>(QKV, Vt, Opart, mlpart);
  attn_combine_kernel<<<2048, 256, 0, stream>>>(Opart, mlpart, Cc);

  // output projection
  gemm_bt_kernel<0><<<dim3(512 / 64, 4096 / 64), 256, 0, stream>>>(
      Cc, BTo, bo, nullptr, out, 4096, 512, 512);
}

// Round 5
// 81.444 us; speedup vs baseline: 1.0209x; 1.0209x over previous
//
#include <hip/hip_runtime.h>

typedef unsigned short u16;
typedef unsigned int u32;
typedef __attribute__((ext_vector_type(8))) __bf16 bf16x8;
typedef __attribute__((ext_vector_type(4))) float f32x4;
typedef __attribute__((ext_vector_type(16))) float f32x16;
typedef __attribute__((ext_vector_type(4))) u32 u32x4;

#if __has_builtin(__builtin_amdgcn_exp2f)
#define EXP2F(x) __builtin_amdgcn_exp2f(x)
#else
#define EXP2F(x) exp2f(x)
#endif

// 0.125 (1/sqrt(64)) * log2(e): folded into Wq/bq so scores are in exp2 domain
#define SC_Q 0.18033688011112042f

static __device__ __forceinline__ u16 f2bf(float f) {
  unsigned u = __builtin_bit_cast(unsigned, f);
  u += 0x7fffu + ((u >> 16) & 1u);
  return (u16)(u >> 16);
}

static __device__ __forceinline__ f32x4 mfma16(bf16x8 a, bf16x8 b, f32x4 c) {
  return __builtin_amdgcn_mfma_f32_16x16x32_bf16(a, b, c, 0, 0, 0);
}
static __device__ __forceinline__ f32x16 mfma32(bf16x8 a, bf16x8 b, f32x16 c) {
  return __builtin_amdgcn_mfma_f32_32x32x16_bf16(a, b, c, 0, 0, 0);
}

static __device__ __forceinline__ u32 cvtpk(float lo, float hi_) {
  u32 r;
  asm("v_cvt_pk_bf16_f32 %0, %1, %2" : "=v"(r) : "v"(lo), "v"(hi_));
  return r;
}

static __device__ __forceinline__ void barrier_raw() {
  asm volatile("" ::: "memory");
  __builtin_amdgcn_s_barrier();
  asm volatile("" ::: "memory");
}

static __device__ __forceinline__ void gload_lds16(const u16* g, u16* l) {
  __builtin_amdgcn_global_load_lds((const __attribute__((address_space(1))) u32*)g,
                                   (__attribute__((address_space(3))) u32*)l, 16, 0, 0);
}

// ---------------- pack kernels ----------------
__global__ void pack_x_kernel(const float* __restrict__ x, u16* __restrict__ xb, int n) {
  int idx = blockIdx.x * 256 + threadIdx.x;
  if (idx < n) xb[idx] = f2bf(x[idx]);
}

// fused weight/bias pack: BTqkv[n][d] (n=t*512+h*64+e, Wq*SC_Q), BTo[n][d]=Wo[d][n], bqkv
__global__ void pack_w_kernel(const float* __restrict__ Wq, const float* __restrict__ Wk,
                              const float* __restrict__ Wv, const float* __restrict__ Wo,
                              const float* __restrict__ bq, const float* __restrict__ bk,
                              const float* __restrict__ bv, u16* __restrict__ BTqkv,
                              u16* __restrict__ BTo, float* __restrict__ bqkv) {
  int idx = blockIdx.x * 256 + threadIdx.x;
  if (idx < 1536 * 512) {
    int n = idx >> 9, d = idx & 511;
    int t = n >> 9, rem = n & 511;
    int h = rem >> 6, e = rem & 63;
    const float* W = (t == 0) ? Wq : ((t == 1) ? Wk : Wv);
    float sc = (t == 0) ? SC_Q : 1.0f;
    BTqkv[idx] = f2bf(W[((size_t)h * 512 + d) * 64 + e] * sc);
  } else if (idx < 1536 * 512 + 512 * 512) {
    int j = idx - 1536 * 512;
    int n = j >> 9, d = j & 511;
    BTo[j] = f2bf(Wo[(size_t)d * 512 + n]);
  } else if (idx < 1536 * 512 + 512 * 512 + 1536) {
    int j = idx - (1536 * 512 + 512 * 512);
    int t = j >> 9, rem = j & 511;
    float v = (t == 0 ? bq : (t == 1 ? bk : bv))[rem];
    bqkv[j] = v * (t == 0 ? SC_Q : 1.0f);
  }
}

// V [4096][1536 @1024+h*64] -> Vt [(b*8+h)*64+e][1024]
__global__ __launch_bounds__(256) void transpose_v_kernel(const u16* __restrict__ QKV,
                                                          u16* __restrict__ Vt) {
  __shared__ u16 t[64][72];
  const int tid = threadIdx.x;
  const int s0 = blockIdx.x * 64;
  const int bh = blockIdx.y;
  const int h = bh & 7, b = bh >> 3;
#pragma unroll
  for (int c2 = 0; c2 < 2; ++c2) {
    int slot = c2 * 256 + tid;
    int sr = slot >> 3, e8 = (slot & 7) * 8;
    uint4 vv = *reinterpret_cast<const uint4*>(
        QKV + (size_t)(b * 1024 + s0 + sr) * 1536 + 1024 + h * 64 + e8);
    *reinterpret_cast<uint4*>(&t[sr][e8]) = vv;
  }
  __syncthreads();
#pragma unroll
  for (int c2 = 0; c2 < 2; ++c2) {
    int slot = c2 * 256 + tid;
    int er = slot >> 3, j8 = (slot & 7) * 8;
    u16 tmp[8];
#pragma unroll
    for (int k = 0; k < 8; ++k) tmp[k] = t[j8 + k][er];
    *reinterpret_cast<uint4*>(Vt + (size_t)(bh * 64 + er) * 1024 + s0 + j8) =
        *reinterpret_cast<const uint4*>(tmp);
  }
}

// ------- GEMM m97-style: C[M][N] = A[M][K] @ BT[N][K]^T + bias -------
// 128x128 tile, BK=64, 256 thr = 4 waves (2x2), per-wave 64x64 = 4x4 16x16x32 frags,
// global_load_lds width-16 staging into linear LDS, 2-barrier loop.
template <int OUT_BF16>
__global__ __launch_bounds__(256) void gemm128_kernel(
    const u16* __restrict__ A, const u16* __restrict__ BT, const float* __restrict__ bias,
    u16* __restrict__ Cb, float* __restrict__ Cf, int M, int N, int K) {
  __shared__ __align__(16) u16 Al[128 * 64];
  __shared__ __align__(16) u16 Bl[128 * 64];
  const int tid = threadIdx.x;
  const int w = tid >> 6, lane = tid & 63, g = lane >> 4, i = lane & 15;
  const int m0 = blockIdx.y * 128, n0 = blockIdx.x * 128;
  const int wr = (w >> 1) * 64, wc = (w & 1) * 64;

  f32x4 acc[4][4];
#pragma unroll
  for (int a = 0; a < 4; ++a)
#pragma unroll
    for (int b = 0; b < 4; ++b) acc[a][b] = f32x4{0.f, 0.f, 0.f, 0.f};

  // staging: slot = it*256+tid; row = slot>>3, colblk = slot&7 (8x16B per 64-col row)
  // LDS dst byte = slot*16 = wave-uniform + lane*16  (global_load_lds constraint OK)
  const u16* ag[4];
  const u16* bg[4];
#pragma unroll
  for (int it = 0; it < 4; ++it) {
    const int slot = it * 256 + tid;
    const int row = slot >> 3, cb = slot & 7;
    ag[it] = A + (size_t)(m0 + row) * K + cb * 8;
    bg[it] = BT + (size_t)(n0 + row) * K + cb * 8;
  }

  for (int k0 = 0; k0 < K; k0 += 64) {
    __syncthreads();  // all waves done reading previous tile
#pragma unroll
    for (int it = 0; it < 4; ++it) {
      const int slot = it * 256 + tid;
      gload_lds16(ag[it] + k0, &Al[slot * 8]);
      gload_lds16(bg[it] + k0, &Bl[slot * 8]);
    }
    __syncthreads();  // hipcc emits s_waitcnt vmcnt(0) before s_barrier -> LDS ready
#pragma unroll
    for (int ks = 0; ks < 2; ++ks) {
      bf16x8 af[4], bf[4];
#pragma unroll
      for (int mf = 0; mf < 4; ++mf)
        af[mf] =
            *reinterpret_cast<const bf16x8*>(&Al[(wr + mf * 16 + i) * 64 + ks * 32 + 8 * g]);
#pragma unroll
      for (int nf = 0; nf < 4; ++nf)
        bf[nf] =
            *reinterpret_cast<const bf16x8*>(&Bl[(wc + nf * 16 + i) * 64 + ks * 32 + 8 * g]);
#pragma unroll
      for (int mf = 0; mf < 4; ++mf)
#pragma unroll
        for (int nf = 0; nf < 4; ++nf) acc[mf][nf] = mfma16(af[mf], bf[nf], acc[mf][nf]);
    }
  }

#pragma unroll
  for (int nf = 0; nf < 4; ++nf) {
    const int col = n0 + wc + nf * 16 + i;
    const float bb = bias[col];
#pragma unroll
    for (int mf = 0; mf < 4; ++mf) {
#pragma unroll
      for (int r = 0; r < 4; ++r) {
        const int row = m0 + wr + mf * 16 + 4 * g + r;
        const float v = acc[mf][nf][r] + bb;
        if (OUT_BF16)
          Cb[(size_t)row * N + col] = f2bf(v);
        else
          Cf[(size_t)row * N + col] = v;
      }
    }
  }
}

// ---------------- attention v3: 32x32 swapped-QK, 4-way KV split ----------------
// grid (h=8, qt=8, b*4+s=16); 256 thr = 4 waves, wave w owns q rows [q0w, q0w+32)
// each block processes keys [s*256, s*256+256), writes partial O (f32) + (m,l)
__global__ __launch_bounds__(256) void attn3_kernel(const u16* __restrict__ QKV,
                                                    const u16* __restrict__ Vt,
                                                    float* __restrict__ Opart,
                                                    float* __restrict__ mlpart) {
  __shared__ __align__(16) u16 Kl[2][4096];  // [64 j][8 eb-blocks of 8] XOR-swizzled
  __shared__ __align__(16) u16 Vl[2][4096];  // [64 e][8 jb-blocks of 8] XOR-swizzled

  const int tid = threadIdx.x;
  const int w = tid >> 6, lane = tid & 63;
  const int col = lane & 31, hi = lane >> 5;
  const int h = blockIdx.x;                 // XCD = flat%8 = h: per-XCD K/V locality
  const int zz = blockIdx.z;
  const int b = zz >> 2, s = zz & 3;
  const int bh = b * 8 + h;
  const int q0w = blockIdx.y * 128 + w * 32;
  const int kvlo = s * 256;
  const int hm = (h < 4) ? h : 4;
  const int band = 1 << hm;
  const int modm = (2 << hm) - 1;
  const int qrow = q0w + col;

  // Q fragments (B-operand): lane holds Q[qrow][16*et + 8*hi + b]
  bf16x8 qf[4];
  const size_t qoff = (size_t)(b * 1024 + qrow) * 1536 + h * 64 + 8 * hi;
#pragma unroll
  for (int et = 0; et < 4; ++et)
    qf[et] = *reinterpret_cast<const bf16x8*>(QKV + qoff + 16 * et);

  // dilation bias per C-reg r (invariant across kv tiles: 64 % 2^(hm+1) == 0)
  float bias[16];
#pragma unroll
  for (int r = 0; r < 16; ++r) {
    int c = (r & 3) + 8 * (r >> 2) + 4 * hi;
    bias[r] = (((qrow - c) & modm) == 0) ? 0.f : -1e30f;
  }

  f32x16 accO0 = {}, accO1 = {};
  float m_run = -1e30f, l_run = 0.f;

  // staging: slot -> linear LDS (slot*16B); global source pre-swizzled (rule #21)
  const int slot0 = tid, slot1 = tid + 256;
  const int kj0 = slot0 >> 3, keb0 = (slot0 & 7) ^ (kj0 & 7);
  const int kj1 = slot1 >> 3, keb1 = (slot1 & 7) ^ (kj1 & 7);
  const u16* kg0 = QKV + (size_t)(b * 1024 + kj0) * 1536 + 512 + h * 64 + keb0 * 8;
  const u16* kg1 = QKV + (size_t)(b * 1024 + kj1) * 1536 + 512 + h * 64 + keb1 * 8;
  const u16* vg0 = Vt + (size_t)(bh * 64 + kj0) * 1024 + keb0 * 8;  // e=kj0, jb=keb0
  const u16* vg1 = Vt + (size_t)(bh * 64 + kj1) * 1024 + keb1 * 8;

#define STAGE(bi, kv0)                                                  \
  do {                                                                  \
    gload_lds16(kg0 + (size_t)(kv0) * 1536, &Kl[bi][slot0 * 8]);        \
    gload_lds16(kg1 + (size_t)(kv0) * 1536, &Kl[bi][slot1 * 8]);        \
    gload_lds16(vg0 + (kv0), &Vl[bi][slot0 * 8]);                       \
    gload_lds16(vg1 + (kv0), &Vl[bi][slot1 * 8]);                       \
  } while (0)

  STAGE(0, kvlo);
  int buf = 0;

  for (int t = 0; t < 4; ++t) {
    const int kv0 = kvlo + t * 64;
    if (t < 3) {
      STAGE(buf ^ 1, kv0 + 64);
      asm volatile("s_waitcnt vmcnt(4)" ::: "memory");
    } else {
      asm volatile("s_waitcnt vmcnt(0)" ::: "memory");
    }
    barrier_raw();

    const u16* Kb = Kl[buf];
    const u16* Vb = Vl[buf];

    // QK^T swapped: s = mfma(K, Q); D[m=j][n=q], lane: n=col, m=crow(r,hi)
    f32x16 s0 = {}, s1 = {};
#pragma unroll
    for (int et = 0; et < 4; ++et) {
      const int sw = ((2 * et + hi) ^ (col & 7)) << 3;
      bf16x8 kf0 = *reinterpret_cast<const bf16x8*>(&Kb[col * 64 + sw]);
      bf16x8 kf1 = *reinterpret_cast<const bf16x8*>(&Kb[(col + 32) * 64 + sw]);
      s0 = mfma32(kf0, qf[et], s0);
      s1 = mfma32(kf1, qf[et], s1);
    }

    // mask (scores already in exp2 domain)
    float p[32];
    const int dq = qrow - kv0;
    const bool near = (q0w <= kv0 + 63 + band) && (kv0 <= q0w + 31 + band);
    if (near) {
#pragma unroll
      for (int r = 0; r < 16; ++r) {
        const int c = (r & 3) + 8 * (r >> 2) + 4 * hi;
        int d0 = dq - c, d1 = d0 - 32;
        d0 = d0 < 0 ? -d0 : d0;
        d1 = d1 < 0 ? -d1 : d1;
        p[r] = (d0 <= band) ? s0[r] : s0[r] + bias[r];
        p[r + 16] = (d1 <= band) ? s1[r] : s1[r] + bias[r];
      }
    } else {
#pragma unroll
      for (int r = 0; r < 16; ++r) {
        p[r] = s0[r] + bias[r];
        p[r + 16] = s1[r] + bias[r];
      }
    }

    // row max: tree reduce (5 dep levels) + lane^32 combine
    float tr[16];
#pragma unroll
    for (int j = 0; j < 16; ++j) tr[j] = fmaxf(p[j], p[j + 16]);
#pragma unroll
    for (int st = 8; st >= 1; st >>= 1)
#pragma unroll
      for (int j = 0; j < st; ++j) tr[j] = fmaxf(tr[j], tr[j + st]);
    float mu = fmaxf(tr[0], __shfl_xor(tr[0], 32));

    // defer-max (T13): rescale only on real growth
    if (__any(mu > m_run + 8.f)) {
      float mn = fmaxf(m_run, mu);
      float corr = EXP2F(m_run - mn);
      m_run = mn;
      l_run *= corr;
#pragma unroll
      for (int j = 0; j < 16; ++j) {
        accO0[j] *= corr;
        accO1[j] *= corr;
      }
    }

#pragma unroll
    for (int j = 0; j < 32; ++j) p[j] = EXP2F(p[j] - m_run);
    float ts[16];
#pragma unroll
    for (int j = 0; j < 16; ++j) ts[j] = p[j] + p[j + 16];
#pragma unroll
    for (int st = 8; st >= 1; st >>= 1)
#pragma unroll
      for (int j = 0; j < st; ++j) ts[j] += ts[j + st];
    l_run += ts[0] + __shfl_xor(ts[0], 32);

    // P -> A-frag in-register (cvt_pk + shfl_xor lane^32 exchange), then PV
#pragma unroll
    for (int kt = 0; kt < 4; ++kt) {
      const float* pp = (kt < 2) ? p : p + 16;  // mt = kt>>1 (compile-time)
      const int R = (kt & 1) * 8;
      u32 A0 = cvtpk(pp[R + 0], pp[R + 1]);
      u32 A1 = cvtpk(pp[R + 2], pp[R + 3]);
      u32 B0 = cvtpk(pp[R + 4], pp[R + 5]);
      u32 B1 = cvtpk(pp[R + 6], pp[R + 7]);
      u32 xA0 = __shfl_xor(A0, 32), xA1 = __shfl_xor(A1, 32);
      u32 xB0 = __shfl_xor(B0, 32), xB1 = __shfl_xor(B1, 32);
      // hi=0 lane supplies k=0..7 -> keys 16kt+0..7  = {own A-words, partner A-words}
      // hi=1 lane supplies k=8..15 -> keys 16kt+8..15 = {partner B-words, own B-words}
      u32 w0 = hi ? xB0 : A0;
      u32 w1 = hi ? xB1 : A1;
      u32 w2 = hi ? B0 : xA0;
      u32 w3 = hi ? B1 : xA1;
      u32x4 pu = {w0, w1, w2, w3};
      bf16x8 paf = __builtin_bit_cast(bf16x8, pu);
      const int jb = 2 * kt + hi;
      {
        const int erow = col;  // nt = 0
        bf16x8 vf = *reinterpret_cast<const bf16x8*>(&Vb[erow * 64 + ((jb ^ (erow & 7)) << 3)]);
        accO0 = mfma32(paf, vf, accO0);
      }
      {
        const int erow = 32 + col;  // nt = 1
        bf16x8 vf = *reinterpret_cast<const bf16x8*>(&Vb[erow * 64 + ((jb ^ (erow & 7)) << 3)]);
        accO1 = mfma32(paf, vf, accO1);
      }
    }

    barrier_raw();
    buf ^= 1;
  }
#undef STAGE

  // epilogue: write unnormalized partial O (f32) + per-row (m,l)
  const size_t obase = (size_t)(s * 32 + bh) * 1024 + q0w;
  if (lane < 32) {
    float2 ml2 = {m_run, l_run};
    *reinterpret_cast<float2*>(&mlpart[(obase + col) * 2]) = ml2;
  }
#pragma unroll
  for (int r = 0; r < 16; ++r) {
    const int c = (r & 3) + 8 * (r >> 2) + 4 * hi;
    float* orow = Opart + (obase + c) * 64;
    orow[col] = accO0[r];
    orow[32 + col] = accO1[r];
  }
}

// ---------------- combine: merge 4 KV-split partials, write bf16 concat ----------------
__global__ __launch_bounds__(256) void attn_combine_kernel(const float* __restrict__ Opart,
                                                           const float* __restrict__ mlpart,
                                                           u16* __restrict__ Cc) {
  const int gid = blockIdx.x * 256 + threadIdx.x;  // 32768 rows * 16 e-quads
  const int rg = gid >> 4;                         // bh*1024 + qrow
  const int e0 = (gid & 15) * 4;
  float m[4], l[4];
#pragma unroll
  for (int s2 = 0; s2 < 4; ++s2) {
    float2 ml2 = *reinterpret_cast<const float2*>(&mlpart[((size_t)s2 * 32768 + rg) * 2]);
    m[s2] = ml2.x;
    l[s2] = ml2.y;
  }
  const float M = fmaxf(fmaxf(m[0], m[1]), fmaxf(m[2], m[3]));
  float L = 0.f, wsc[4];
#pragma unroll
  for (int s2 = 0; s2 < 4; ++s2) {
    wsc[s2] = EXP2F(m[s2] - M);
    L += l[s2] * wsc[s2];
  }
  float4 o = {0.f, 0.f, 0.f, 0.f};
#pragma unroll
  for (int s2 = 0; s2 < 4; ++s2) {
    float4 op = *reinterpret_cast<const float4*>(&Opart[((size_t)s2 * 32768 + rg) * 64 + e0]);
    o.x += op.x * wsc[s2];
    o.y += op.y * wsc[s2];
    o.z += op.z * wsc[s2];
    o.w += op.w * wsc[s2];
  }
  const float inv = 1.0f / L;
  const int bh = rg >> 10, qr = rg & 1023;
  u16 ob[4] = {f2bf(o.x * inv), f2bf(o.y * inv), f2bf(o.z * inv), f2bf(o.w * inv)};
  *reinterpret_cast<uint2*>(&Cc[(size_t)((bh >> 3) * 1024 + qr) * 512 + (bh & 7) * 64 + e0]) =
      *reinterpret_cast<const uint2*>(ob);
}

// ---------------- launch ----------------
extern "C" void kernel_launch(void* const* d_in, const int* in_sizes, int n_in,
                              void* d_out, int out_size, void* d_ws, size_t ws_size,
                              hipStream_t stream) {
  const float* x = (const float*)d_in[0];
  const float* Wq = (const float*)d_in[1];
  const float* bq = (const float*)d_in[2];
  const float* Wk = (const float*)d_in[3];
  const float* bk = (const float*)d_in[4];
  const float* Wv = (const float*)d_in[5];
  const float* bv = (const float*)d_in[6];
  const float* Wo = (const float*)d_in[7];
  const float* bo = (const float*)d_in[8];
  float* out = (float*)d_out;

  char* ws = (char*)d_ws;
  u16* xb = (u16*)(ws);                     // 4 MB   [4096][512]
  u16* BTqkv = (u16*)(ws + (4u << 20));     // 1.5 MB [1536][512]
  u16* BTo = (u16*)(ws + (6u << 20));       // 0.5 MB [512][512]
  float* bqkv = (float*)(ws + (7u << 20));  // 6 KB
  u16* QKV = (u16*)(ws + (8u << 20));       // 12.6 MB [4096][1536]
  u16* Cc = (u16*)(ws + (21u << 20));       // 4 MB   [4096][512]
  u16* Vt = (u16*)(ws + (25u << 20));       // 4 MB   [32*64][1024]
  float* Opart = (float*)(ws + (32u << 20));   // 32 MB [4 splits][32 bh][1024][64]
  float* mlpart = (float*)(ws + (64u << 20));  // 1 MB  [4 splits][32 bh][1024][2]

  const int NX = 4096 * 512;
  pack_x_kernel<<<(NX + 255) / 256, 256, 0, stream>>>(x, xb, NX);
  const int NW = 1536 * 512 + 512 * 512 + 1536;
  pack_w_kernel<<<(NW + 255) / 256, 256, 0, stream>>>(Wq, Wk, Wv, Wo, bq, bk, bv, BTqkv,
                                                      BTo, bqkv);

  // QKV projection: [4096,512] @ [512,1536] -> bf16 QKV (Wq pre-scaled)
  gemm128_kernel<1><<<dim3(1536 / 128, 4096 / 128), 256, 0, stream>>>(
      xb, BTqkv, bqkv, QKV, nullptr, 4096, 1536, 512);

  // V -> Vt
  transpose_v_kernel<<<dim3(16, 32), 256, 0, stream>>>(QKV, Vt);

  // attention: 4-way KV split (grid x=h for XCD L2 locality)
  attn3_kernel<<<dim3(8, 8, 16), 256, 0, stream>>>(QKV, Vt, Opart, mlpart);
  attn_combine_kernel<<<2048, 256, 0, stream>>>(Opart, mlpart, Cc);

  // output projection: [4096,512] @ [512,512] -> f32 out
  gemm128_kernel<0><<<dim3(512 / 128, 4096 / 128), 256, 0, stream>>>(
      Cc, BTo, bo, nullptr, out, 4096, 512, 512);
}

// Round 6
// 70.980 us; speedup vs baseline: 1.1714x; 1.1474x over previous
//
#include <hip/hip_runtime.h>

typedef unsigned short u16;
typedef unsigned int u32;
typedef __attribute__((ext_vector_type(8))) __bf16 bf16x8;
typedef __attribute__((ext_vector_type(4))) float f32x4;
typedef __attribute__((ext_vector_type(16))) float f32x16;
typedef __attribute__((ext_vector_type(4))) u32 u32x4;

#if __has_builtin(__builtin_amdgcn_exp2f)
#define EXP2F(x) __builtin_amdgcn_exp2f(x)
#else
#define EXP2F(x) exp2f(x)
#endif

// 0.125 (1/sqrt(64)) * log2(e): folded into Wq/bq so scores are in exp2 domain
#define SC_Q 0.18033688011112042f

static __device__ __forceinline__ u16 f2bf(float f) {
  unsigned u = __builtin_bit_cast(unsigned, f);
  u += 0x7fffu + ((u >> 16) & 1u);
  return (u16)(u >> 16);
}
static __device__ __forceinline__ float bf2f(u16 v) {
  return __builtin_bit_cast(float, (u32)v << 16);
}

static __device__ __forceinline__ f32x4 mfma16(bf16x8 a, bf16x8 b, f32x4 c) {
  return __builtin_amdgcn_mfma_f32_16x16x32_bf16(a, b, c, 0, 0, 0);
}
static __device__ __forceinline__ f32x16 mfma32(bf16x8 a, bf16x8 b, f32x16 c) {
  return __builtin_amdgcn_mfma_f32_32x32x16_bf16(a, b, c, 0, 0, 0);
}

static __device__ __forceinline__ u32 cvtpk(float lo, float hi_) {
  u32 r;
  asm("v_cvt_pk_bf16_f32 %0, %1, %2" : "=v"(r) : "v"(lo), "v"(hi_));
  return r;
}

static __device__ __forceinline__ void barrier_raw() {
  asm volatile("" ::: "memory");
  __builtin_amdgcn_s_barrier();
  asm volatile("" ::: "memory");
}

static __device__ __forceinline__ void gload_lds16(const u16* g, u16* l) {
  __builtin_amdgcn_global_load_lds((const __attribute__((address_space(1))) u32*)g,
                                   (__attribute__((address_space(3))) u32*)l, 16, 0, 0);
}

// ---------------- pack kernels ----------------
__global__ void pack_x_kernel(const float* __restrict__ x, u16* __restrict__ xb, int n) {
  int idx = blockIdx.x * 256 + threadIdx.x;
  if (idx < n) xb[idx] = f2bf(x[idx]);
}

// fused weight/bias pack: BTqkv[n][d] (n=t*512+h*64+e, Wq*SC_Q), BTo[n][d]=Wo[d][n], bqkv
__global__ void pack_w_kernel(const float* __restrict__ Wq, const float* __restrict__ Wk,
                              const float* __restrict__ Wv, const float* __restrict__ Wo,
                              const float* __restrict__ bq, const float* __restrict__ bk,
                              const float* __restrict__ bv, u16* __restrict__ BTqkv,
                              u16* __restrict__ BTo, float* __restrict__ bqkv) {
  int idx = blockIdx.x * 256 + threadIdx.x;
  if (idx < 1536 * 512) {
    int n = idx >> 9, d = idx & 511;
    int t = n >> 9, rem = n & 511;
    int h = rem >> 6, e = rem & 63;
    const float* W = (t == 0) ? Wq : ((t == 1) ? Wk : Wv);
    float sc = (t == 0) ? SC_Q : 1.0f;
    BTqkv[idx] = f2bf(W[((size_t)h * 512 + d) * 64 + e] * sc);
  } else if (idx < 1536 * 512 + 512 * 512) {
    int j = idx - 1536 * 512;
    int n = j >> 9, d = j & 511;
    BTo[j] = f2bf(Wo[(size_t)d * 512 + n]);
  } else if (idx < 1536 * 512 + 512 * 512 + 1536) {
    int j = idx - (1536 * 512 + 512 * 512);
    int t = j >> 9, rem = j & 511;
    float v = (t == 0 ? bq : (t == 1 ? bk : bv))[rem];
    bqkv[j] = v * (t == 0 ? SC_Q : 1.0f);
  }
}

// ------- QKV GEMM, 128x64 tile: QK[m][n] = x[m][:] @ BTqkv[n][:]; V cols -> Vt -------
// grid (24, 32); 4 waves 2x2; wave: 64x32 out = 4x2 16x16x32 frags. BK=64.
__global__ __launch_bounds__(256) void gemm_qkv_kernel(const u16* __restrict__ A,
                                                       const u16* __restrict__ BT,
                                                       const float* __restrict__ bias,
                                                       u16* __restrict__ QK,
                                                       u16* __restrict__ Vt) {
  __shared__ __align__(16) u16 Al[128 * 64];
  __shared__ __align__(16) u16 Bl[64 * 64];
  const int K = 512;
  const int tid = threadIdx.x;
  const int w = tid >> 6, lane = tid & 63, g = lane >> 4, i = lane & 15;
  const int m0 = blockIdx.y * 128, n0 = blockIdx.x * 64;
  const int wr = (w >> 1) * 64, wc = (w & 1) * 32;

  f32x4 acc[4][2];
#pragma unroll
  for (int a = 0; a < 4; ++a)
#pragma unroll
    for (int b = 0; b < 2; ++b) acc[a][b] = f32x4{0.f, 0.f, 0.f, 0.f};

  const u16* agp[4];
  const u16* bgp[2];
#pragma unroll
  for (int it = 0; it < 4; ++it) {
    const int slot = it * 256 + tid;
    agp[it] = A + (size_t)(m0 + (slot >> 3)) * K + (slot & 7) * 8;
  }
#pragma unroll
  for (int it = 0; it < 2; ++it) {
    const int slot = it * 256 + tid;
    bgp[it] = BT + (size_t)(n0 + (slot >> 3)) * K + (slot & 7) * 8;
  }

  for (int k0 = 0; k0 < K; k0 += 64) {
    __syncthreads();
#pragma unroll
    for (int it = 0; it < 4; ++it) gload_lds16(agp[it] + k0, &Al[(it * 256 + tid) * 8]);
#pragma unroll
    for (int it = 0; it < 2; ++it) gload_lds16(bgp[it] + k0, &Bl[(it * 256 + tid) * 8]);
    __syncthreads();
#pragma unroll
    for (int ks = 0; ks < 2; ++ks) {
      bf16x8 af[4], bf[2];
#pragma unroll
      for (int mf = 0; mf < 4; ++mf)
        af[mf] =
            *reinterpret_cast<const bf16x8*>(&Al[(wr + mf * 16 + i) * 64 + ks * 32 + 8 * g]);
#pragma unroll
      for (int nf = 0; nf < 2; ++nf)
        bf[nf] =
            *reinterpret_cast<const bf16x8*>(&Bl[(wc + nf * 16 + i) * 64 + ks * 32 + 8 * g]);
#pragma unroll
      for (int mf = 0; mf < 4; ++mf)
#pragma unroll
        for (int nf = 0; nf < 2; ++nf) acc[mf][nf] = mfma16(af[mf], bf[nf], acc[mf][nf]);
    }
  }

  if (n0 < 1024) {
    // Q/K region: store to compact QK [4096][1024]
#pragma unroll
    for (int nf = 0; nf < 2; ++nf) {
      const int col = n0 + wc + nf * 16 + i;
      const float bb = bias[col];
#pragma unroll
      for (int mf = 0; mf < 4; ++mf) {
#pragma unroll
        for (int r = 0; r < 4; ++r) {
          const int row = m0 + wr + mf * 16 + 4 * g + r;
          QK[(size_t)row * 1024 + col] = f2bf(acc[mf][nf][r] + bb);
        }
      }
    }
  } else {
    // V region: store transposed Vt[b*512 + vcol][seq]; 4 consecutive seq per frag
    const int b = m0 >> 10;
    const int s0b = (m0 & 1023) + wr;
#pragma unroll
    for (int nf = 0; nf < 2; ++nf) {
      const int col = n0 + wc + nf * 16 + i;
      const float bb = bias[col];
      const int vcol = col - 1024;
#pragma unroll
      for (int mf = 0; mf < 4; ++mf) {
        u16 pk[4];
#pragma unroll
        for (int r = 0; r < 4; ++r) pk[r] = f2bf(acc[mf][nf][r] + bb);
        const int ss = s0b + mf * 16 + 4 * g;
        *reinterpret_cast<uint2*>(&Vt[(size_t)(b * 512 + vcol) * 1024 + ss]) =
            *reinterpret_cast<const uint2*>(pk);
      }
    }
  }
}

// ------- out projection, 128x64 tile: out[m][n] = Cc[m][:] @ BTo[n][:] + bo -------
__global__ __launch_bounds__(256) void gemm_out_kernel(const u16* __restrict__ A,
                                                       const u16* __restrict__ BT,
                                                       const float* __restrict__ bias,
                                                       float* __restrict__ Cf) {
  __shared__ __align__(16) u16 Al[128 * 64];
  __shared__ __align__(16) u16 Bl[64 * 64];
  const int K = 512;
  const int tid = threadIdx.x;
  const int w = tid >> 6, lane = tid & 63, g = lane >> 4, i = lane & 15;
  const int m0 = blockIdx.y * 128, n0 = blockIdx.x * 64;
  const int wr = (w >> 1) * 64, wc = (w & 1) * 32;

  f32x4 acc[4][2];
#pragma unroll
  for (int a = 0; a < 4; ++a)
#pragma unroll
    for (int b = 0; b < 2; ++b) acc[a][b] = f32x4{0.f, 0.f, 0.f, 0.f};

  const u16* agp[4];
  const u16* bgp[2];
#pragma unroll
  for (int it = 0; it < 4; ++it) {
    const int slot = it * 256 + tid;
    agp[it] = A + (size_t)(m0 + (slot >> 3)) * K + (slot & 7) * 8;
  }
#pragma unroll
  for (int it = 0; it < 2; ++it) {
    const int slot = it * 256 + tid;
    bgp[it] = BT + (size_t)(n0 + (slot >> 3)) * K + (slot & 7) * 8;
  }

  for (int k0 = 0; k0 < K; k0 += 64) {
    __syncthreads();
#pragma unroll
    for (int it = 0; it < 4; ++it) gload_lds16(agp[it] + k0, &Al[(it * 256 + tid) * 8]);
#pragma unroll
    for (int it = 0; it < 2; ++it) gload_lds16(bgp[it] + k0, &Bl[(it * 256 + tid) * 8]);
    __syncthreads();
#pragma unroll
    for (int ks = 0; ks < 2; ++ks) {
      bf16x8 af[4], bf[2];
#pragma unroll
      for (int mf = 0; mf < 4; ++mf)
        af[mf] =
            *reinterpret_cast<const bf16x8*>(&Al[(wr + mf * 16 + i) * 64 + ks * 32 + 8 * g]);
#pragma unroll
      for (int nf = 0; nf < 2; ++nf)
        bf[nf] =
            *reinterpret_cast<const bf16x8*>(&Bl[(wc + nf * 16 + i) * 64 + ks * 32 + 8 * g]);
#pragma unroll
      for (int mf = 0; mf < 4; ++mf)
#pragma unroll
        for (int nf = 0; nf < 2; ++nf) acc[mf][nf] = mfma16(af[mf], bf[nf], acc[mf][nf]);
    }
  }

#pragma unroll
  for (int nf = 0; nf < 2; ++nf) {
    const int col = n0 + wc + nf * 16 + i;
    const float bb = bias[col];
#pragma unroll
    for (int mf = 0; mf < 4; ++mf) {
#pragma unroll
      for (int r = 0; r < 4; ++r) {
        const int row = m0 + wr + mf * 16 + 4 * g + r;
        Cf[(size_t)row * 512 + col] = acc[mf][nf][r] + bb;
      }
    }
  }
}

// ---------------- attention: 32x32 swapped-QK, 4-way KV split ----------------
// grid (h=8, qt=8, b*4+s=16); 256 thr = 4 waves, wave w owns q rows [q0w, q0w+32)
// QK layout: [4096][1024] (Q at col h*64, K at col 512+h*64)
__global__ __launch_bounds__(256) void attn3_kernel(const u16* __restrict__ QK,
                                                    const u16* __restrict__ Vt,
                                                    u16* __restrict__ Opart16,
                                                    float* __restrict__ mlpart) {
  __shared__ __align__(16) u16 Kl[2][4096];  // [64 j][8 eb-blocks of 8] XOR-swizzled
  __shared__ __align__(16) u16 Vl[2][4096];  // [64 e][8 jb-blocks of 8] XOR-swizzled

  const int tid = threadIdx.x;
  const int w = tid >> 6, lane = tid & 63;
  const int col = lane & 31, hi = lane >> 5;
  const int h = blockIdx.x;  // XCD = flat%8 = h: per-XCD K/V locality
  const int zz = blockIdx.z;
  const int b = zz >> 2, s = zz & 3;
  const int bh = b * 8 + h;
  const int q0w = blockIdx.y * 128 + w * 32;
  const int kvlo = s * 256;
  const int hm = (h < 4) ? h : 4;
  const int band = 1 << hm;
  const int modm = (2 << hm) - 1;
  const int qrow = q0w + col;

  // Q fragments (B-operand): lane holds Q[qrow][16*et + 8*hi + b]
  bf16x8 qf[4];
  const size_t qoff = (size_t)(b * 1024 + qrow) * 1024 + h * 64 + 8 * hi;
#pragma unroll
  for (int et = 0; et < 4; ++et)
    qf[et] = *reinterpret_cast<const bf16x8*>(QK + qoff + 16 * et);

  // dilation bias per C-reg r (invariant across kv tiles: 64 % 2^(hm+1) == 0)
  float bias[16];
#pragma unroll
  for (int r = 0; r < 16; ++r) {
    int c = (r & 3) + 8 * (r >> 2) + 4 * hi;
    bias[r] = (((qrow - c) & modm) == 0) ? 0.f : -1e30f;
  }

  f32x16 accO0 = {}, accO1 = {};
  float m_run = -1e30f, l_run = 0.f;

  // staging: slot -> linear LDS (slot*16B); global source pre-swizzled (rule #21)
  const int slot0 = tid, slot1 = tid + 256;
  const int kj0 = slot0 >> 3, keb0 = (slot0 & 7) ^ (kj0 & 7);
  const int kj1 = slot1 >> 3, keb1 = (slot1 & 7) ^ (kj1 & 7);
  const u16* kg0 = QK + (size_t)(b * 1024 + kj0) * 1024 + 512 + h * 64 + keb0 * 8;
  const u16* kg1 = QK + (size_t)(b * 1024 + kj1) * 1024 + 512 + h * 64 + keb1 * 8;
  const u16* vg0 = Vt + (size_t)(bh * 64 + kj0) * 1024 + keb0 * 8;  // e=kj0, jb=keb0
  const u16* vg1 = Vt + (size_t)(bh * 64 + kj1) * 1024 + keb1 * 8;

#define STAGE(bi, kv0)                                                  \
  do {                                                                  \
    gload_lds16(kg0 + (size_t)(kv0) * 1024, &Kl[bi][slot0 * 8]);        \
    gload_lds16(kg1 + (size_t)(kv0) * 1024, &Kl[bi][slot1 * 8]);        \
    gload_lds16(vg0 + (kv0), &Vl[bi][slot0 * 8]);                       \
    gload_lds16(vg1 + (kv0), &Vl[bi][slot1 * 8]);                       \
  } while (0)

  STAGE(0, kvlo);
  int buf = 0;

  for (int t = 0; t < 4; ++t) {
    const int kv0 = kvlo + t * 64;
    if (t < 3) {
      STAGE(buf ^ 1, kv0 + 64);
      asm volatile("s_waitcnt vmcnt(4)" ::: "memory");
    } else {
      asm volatile("s_waitcnt vmcnt(0)" ::: "memory");
    }
    barrier_raw();

    const u16* Kb = Kl[buf];
    const u16* Vb = Vl[buf];

    // QK^T swapped: s = mfma(K, Q); D[m=j][n=q], lane: n=col, m=crow(r,hi)
    f32x16 s0 = {}, s1 = {};
    __builtin_amdgcn_s_setprio(1);
#pragma unroll
    for (int et = 0; et < 4; ++et) {
      const int sw = ((2 * et + hi) ^ (col & 7)) << 3;
      bf16x8 kf0 = *reinterpret_cast<const bf16x8*>(&Kb[col * 64 + sw]);
      bf16x8 kf1 = *reinterpret_cast<const bf16x8*>(&Kb[(col + 32) * 64 + sw]);
      s0 = mfma32(kf0, qf[et], s0);
      s1 = mfma32(kf1, qf[et], s1);
    }
    __builtin_amdgcn_s_setprio(0);

    // mask (scores already in exp2 domain)
    float p[32];
    const int dq = qrow - kv0;
    const bool near = (q0w <= kv0 + 63 + band) && (kv0 <= q0w + 31 + band);
    if (near) {
#pragma unroll
      for (int r = 0; r < 16; ++r) {
        const int c = (r & 3) + 8 * (r >> 2) + 4 * hi;
        int d0 = dq - c, d1 = d0 - 32;
        d0 = d0 < 0 ? -d0 : d0;
        d1 = d1 < 0 ? -d1 : d1;
        p[r] = (d0 <= band) ? s0[r] : s0[r] + bias[r];
        p[r + 16] = (d1 <= band) ? s1[r] : s1[r] + bias[r];
      }
    } else {
#pragma unroll
      for (int r = 0; r < 16; ++r) {
        p[r] = s0[r] + bias[r];
        p[r + 16] = s1[r] + bias[r];
      }
    }

    // row max: tree reduce (5 dep levels) + lane^32 combine
    float tr[16];
#pragma unroll
    for (int j = 0; j < 16; ++j) tr[j] = fmaxf(p[j], p[j + 16]);
#pragma unroll
    for (int st = 8; st >= 1; st >>= 1)
#pragma unroll
      for (int j = 0; j < st; ++j) tr[j] = fmaxf(tr[j], tr[j + st]);
    float mu = fmaxf(tr[0], __shfl_xor(tr[0], 32));

    // defer-max (T13): rescale only on real growth
    if (__any(mu > m_run + 8.f)) {
      float mn = fmaxf(m_run, mu);
      float corr = EXP2F(m_run - mn);
      m_run = mn;
      l_run *= corr;
#pragma unroll
      for (int j = 0; j < 16; ++j) {
        accO0[j] *= corr;
        accO1[j] *= corr;
      }
    }

#pragma unroll
    for (int j = 0; j < 32; ++j) p[j] = EXP2F(p[j] - m_run);
    float ts[16];
#pragma unroll
    for (int j = 0; j < 16; ++j) ts[j] = p[j] + p[j + 16];
#pragma unroll
    for (int st = 8; st >= 1; st >>= 1)
#pragma unroll
      for (int j = 0; j < st; ++j) ts[j] += ts[j + st];
    l_run += ts[0] + __shfl_xor(ts[0], 32);

    // P -> A-frag in-register (cvt_pk + shfl_xor lane^32 exchange), then PV
#pragma unroll
    for (int kt = 0; kt < 4; ++kt) {
      const float* pp = (kt < 2) ? p : p + 16;  // mt = kt>>1 (compile-time)
      const int R = (kt & 1) * 8;
      u32 A0 = cvtpk(pp[R + 0], pp[R + 1]);
      u32 A1 = cvtpk(pp[R + 2], pp[R + 3]);
      u32 B0 = cvtpk(pp[R + 4], pp[R + 5]);
      u32 B1 = cvtpk(pp[R + 6], pp[R + 7]);
      u32 xA0 = __shfl_xor(A0, 32), xA1 = __shfl_xor(A1, 32);
      u32 xB0 = __shfl_xor(B0, 32), xB1 = __shfl_xor(B1, 32);
      u32 w0 = hi ? xB0 : A0;
      u32 w1 = hi ? xB1 : A1;
      u32 w2 = hi ? B0 : xA0;
      u32 w3 = hi ? B1 : xA1;
      u32x4 pu = {w0, w1, w2, w3};
      bf16x8 paf = __builtin_bit_cast(bf16x8, pu);
      const int jb = 2 * kt + hi;
      __builtin_amdgcn_s_setprio(1);
      {
        const int erow = col;  // nt = 0
        bf16x8 vf = *reinterpret_cast<const bf16x8*>(&Vb[erow * 64 + ((jb ^ (erow & 7)) << 3)]);
        accO0 = mfma32(paf, vf, accO0);
      }
      {
        const int erow = 32 + col;  // nt = 1
        bf16x8 vf = *reinterpret_cast<const bf16x8*>(&Vb[erow * 64 + ((jb ^ (erow & 7)) << 3)]);
        accO1 = mfma32(paf, vf, accO1);
      }
      __builtin_amdgcn_s_setprio(0);
    }

    barrier_raw();
    buf ^= 1;
  }
#undef STAGE

  // epilogue: write unnormalized partial O (bf16) + per-row (m,l) f32
  const size_t obase = (size_t)(s * 32 + bh) * 1024 + q0w;
  if (lane < 32) {
    float2 ml2 = {m_run, l_run};
    *reinterpret_cast<float2*>(&mlpart[(obase + col) * 2]) = ml2;
  }
#pragma unroll
  for (int r = 0; r < 16; ++r) {
    const int c = (r & 3) + 8 * (r >> 2) + 4 * hi;
    u16* orow = Opart16 + (obase + c) * 64;
    orow[col] = f2bf(accO0[r]);
    orow[32 + col] = f2bf(accO1[r]);
  }
}

// ---------------- combine: merge 4 KV-split partials, write bf16 concat ----------------
__global__ __launch_bounds__(256) void attn_combine_kernel(const u16* __restrict__ Opart16,
                                                           const float* __restrict__ mlpart,
                                                           u16* __restrict__ Cc) {
  const int gid = blockIdx.x * 256 + threadIdx.x;  // 32768 rows * 16 e-quads
  const int rg = gid >> 4;                         // bh*1024 + qrow
  const int e0 = (gid & 15) * 4;
  float m[4], l[4];
#pragma unroll
  for (int s2 = 0; s2 < 4; ++s2) {
    float2 ml2 = *reinterpret_cast<const float2*>(&mlpart[((size_t)s2 * 32768 + rg) * 2]);
    m[s2] = ml2.x;
    l[s2] = ml2.y;
  }
  const float M = fmaxf(fmaxf(m[0], m[1]), fmaxf(m[2], m[3]));
  float L = 0.f, wsc[4];
#pragma unroll
  for (int s2 = 0; s2 < 4; ++s2) {
    wsc[s2] = EXP2F(m[s2] - M);
    L += l[s2] * wsc[s2];
  }
  float o0 = 0.f, o1 = 0.f, o2 = 0.f, o3 = 0.f;
#pragma unroll
  for (int s2 = 0; s2 < 4; ++s2) {
    uint2 raw =
        *reinterpret_cast<const uint2*>(&Opart16[((size_t)s2 * 32768 + rg) * 64 + e0]);
    o0 += bf2f((u16)(raw.x & 0xffff)) * wsc[s2];
    o1 += bf2f((u16)(raw.x >> 16)) * wsc[s2];
    o2 += bf2f((u16)(raw.y & 0xffff)) * wsc[s2];
    o3 += bf2f((u16)(raw.y >> 16)) * wsc[s2];
  }
  const float inv = 1.0f / L;
  const int bh = rg >> 10, qr = rg & 1023;
  u16 ob[4] = {f2bf(o0 * inv), f2bf(o1 * inv), f2bf(o2 * inv), f2bf(o3 * inv)};
  *reinterpret_cast<uint2*>(&Cc[(size_t)((bh >> 3) * 1024 + qr) * 512 + (bh & 7) * 64 + e0]) =
      *reinterpret_cast<const uint2*>(ob);
}

// ---------------- launch ----------------
extern "C" void kernel_launch(void* const* d_in, const int* in_sizes, int n_in,
                              void* d_out, int out_size, void* d_ws, size_t ws_size,
                              hipStream_t stream) {
  const float* x = (const float*)d_in[0];
  const float* Wq = (const float*)d_in[1];
  const float* bq = (const float*)d_in[2];
  const float* Wk = (const float*)d_in[3];
  const float* bk = (const float*)d_in[4];
  const float* Wv = (const float*)d_in[5];
  const float* bv = (const float*)d_in[6];
  const float* Wo = (const float*)d_in[7];
  const float* bo = (const float*)d_in[8];
  float* out = (float*)d_out;

  char* ws = (char*)d_ws;
  u16* xb = (u16*)(ws);                     // 4 MB   [4096][512]
  u16* BTqkv = (u16*)(ws + (4u << 20));     // 1.5 MB [1536][512]
  u16* BTo = (u16*)(ws + (6u << 20));       // 0.5 MB [512][512]
  float* bqkv = (float*)(ws + (7u << 20));  // 6 KB
  u16* QK = (u16*)(ws + (8u << 20));        // 8 MB   [4096][1024] (Q | K)
  u16* Cc = (u16*)(ws + (17u << 20));       // 4 MB   [4096][512]
  u16* Vt = (u16*)(ws + (21u << 20));       // 4 MB   [32*64][1024]
  u16* Opart16 = (u16*)(ws + (32u << 20));  // 16 MB  [4 splits][32 bh][1024][64] bf16
  float* mlpart = (float*)(ws + (64u << 20));  // 1 MB [4 splits][32 bh][1024][2]

  const int NX = 4096 * 512;
  pack_x_kernel<<<(NX + 255) / 256, 256, 0, stream>>>(x, xb, NX);
  const int NW = 1536 * 512 + 512 * 512 + 1536;
  pack_w_kernel<<<(NW + 255) / 256, 256, 0, stream>>>(Wq, Wk, Wv, Wo, bq, bk, bv, BTqkv,
                                                      BTo, bqkv);

  // QKV projection (V transposed in epilogue): grid 24x32 = 768 blocks (3/CU)
  gemm_qkv_kernel<<<dim3(24, 32), 256, 0, stream>>>(xb, BTqkv, bqkv, QK, Vt);

  // attention: 4-way KV split (grid x=h for XCD L2 locality)
  attn3_kernel<<<dim3(8, 8, 16), 256, 0, stream>>>(QK, Vt, Opart16, mlpart);
  attn_combine_kernel<<<2048, 256, 0, stream>>>(Opart16, mlpart, Cc);

  // output projection: grid 8x32 = 256 blocks (1/CU)
  gemm_out_kernel<<<dim3(8, 32), 256, 0, stream>>>(Cc, BTo, bo, out);
}

// Round 7
// 68.585 us; speedup vs baseline: 1.2123x; 1.0349x over previous
//
#include <hip/hip_runtime.h>

typedef unsigned short u16;
typedef unsigned int u32;
typedef __attribute__((ext_vector_type(8))) __bf16 bf16x8;
typedef __attribute__((ext_vector_type(4))) float f32x4;
typedef __attribute__((ext_vector_type(16))) float f32x16;
typedef __attribute__((ext_vector_type(4))) u32 u32x4;

#if __has_builtin(__builtin_amdgcn_exp2f)
#define EXP2F(x) __builtin_amdgcn_exp2f(x)
#else
#define EXP2F(x) exp2f(x)
#endif

// 0.125 (1/sqrt(64)) * log2(e): folded into Wq/bq so scores are in exp2 domain
#define SC_Q 0.18033688011112042f

static __device__ __forceinline__ u16 f2bf(float f) {
  unsigned u = __builtin_bit_cast(unsigned, f);
  u += 0x7fffu + ((u >> 16) & 1u);
  return (u16)(u >> 16);
}
static __device__ __forceinline__ float bf2f(u16 v) {
  return __builtin_bit_cast(float, (u32)v << 16);
}

static __device__ __forceinline__ f32x4 mfma16(bf16x8 a, bf16x8 b, f32x4 c) {
  return __builtin_amdgcn_mfma_f32_16x16x32_bf16(a, b, c, 0, 0, 0);
}
static __device__ __forceinline__ f32x16 mfma32(bf16x8 a, bf16x8 b, f32x16 c) {
  return __builtin_amdgcn_mfma_f32_32x32x16_bf16(a, b, c, 0, 0, 0);
}

static __device__ __forceinline__ u32 cvtpk(float lo, float hi_) {
  u32 r;
  asm("v_cvt_pk_bf16_f32 %0, %1, %2" : "=v"(r) : "v"(lo), "v"(hi_));
  return r;
}

static __device__ __forceinline__ void barrier_raw() {
  asm volatile("" ::: "memory");
  __builtin_amdgcn_s_barrier();
  asm volatile("" ::: "memory");
}

static __device__ __forceinline__ void gload_lds16(const u16* g, u16* l) {
  __builtin_amdgcn_global_load_lds((const __attribute__((address_space(1))) u32*)g,
                                   (__attribute__((address_space(3))) u32*)l, 16, 0, 0);
}

// ---------------- pack kernel ----------------
// BTqkv[n][d] (n=t*512+h*64+e, Wq*SC_Q), BTo[n][d]=Wo[d][n], bqkv
__global__ void pack_w_kernel(const float* __restrict__ Wq, const float* __restrict__ Wk,
                              const float* __restrict__ Wv, const float* __restrict__ Wo,
                              const float* __restrict__ bq, const float* __restrict__ bk,
                              const float* __restrict__ bv, u16* __restrict__ BTqkv,
                              u16* __restrict__ BTo, float* __restrict__ bqkv) {
  int idx = blockIdx.x * 256 + threadIdx.x;
  if (idx < 1536 * 512) {
    int n = idx >> 9, d = idx & 511;
    int t = n >> 9, rem = n & 511;
    int h = rem >> 6, e = rem & 63;
    const float* W = (t == 0) ? Wq : ((t == 1) ? Wk : Wv);
    float sc = (t == 0) ? SC_Q : 1.0f;
    BTqkv[idx] = f2bf(W[((size_t)h * 512 + d) * 64 + e] * sc);
  } else if (idx < 1536 * 512 + 512 * 512) {
    int j = idx - 1536 * 512;
    int n = j >> 9, d = j & 511;
    BTo[j] = f2bf(Wo[(size_t)d * 512 + n]);
  } else if (idx < 1536 * 512 + 512 * 512 + 1536) {
    int j = idx - (1536 * 512 + 512 * 512);
    int t = j >> 9, rem = j & 511;
    float v = (t == 0 ? bq : (t == 1 ? bk : bv))[rem];
    bqkv[j] = v * (t == 0 ? SC_Q : 1.0f);
  }
}

// ------- QKV GEMM (fused f32->bf16 A-pack), 128x64 tile, dbuf + counted vmcnt -------
// grid (24, 32); 4 waves 2x2; wave: 64x32 out = 4x2 16x16x32 frags. BK=64.
// A staged from f32 x via regs (8 float4) -> cvt_pk -> ds_write; B via global_load_lds.
__global__ __launch_bounds__(256) void gemm_qkv_kernel(const float* __restrict__ X,
                                                       const u16* __restrict__ BT,
                                                       const float* __restrict__ bias,
                                                       u16* __restrict__ QK,
                                                       u16* __restrict__ Vt) {
  __shared__ __align__(16) u16 Al[2][128 * 64];
  __shared__ __align__(16) u16 Bl[2][64 * 64];
  const int K = 512;
  const int tid = threadIdx.x;
  const int w = tid >> 6, lane = tid & 63, g = lane >> 4, i = lane & 15;
  const int m0 = blockIdx.y * 128, n0 = blockIdx.x * 64;
  const int wr = (w >> 1) * 64, wc = (w & 1) * 32;

  f32x4 acc[4][2];
#pragma unroll
  for (int a = 0; a < 4; ++a)
#pragma unroll
    for (int b = 0; b < 2; ++b) acc[a][b] = f32x4{0.f, 0.f, 0.f, 0.f};

  const float* xg[4];
#pragma unroll
  for (int it = 0; it < 4; ++it) {
    const int slot = it * 256 + tid;
    xg[it] = X + (size_t)(m0 + (slot >> 3)) * K + (slot & 7) * 8;
  }
  const u16* bgp[2];
#pragma unroll
  for (int it = 0; it < 2; ++it) {
    const int slot = it * 256 + tid;
    bgp[it] = BT + (size_t)(n0 + (slot >> 3)) * K + (slot & 7) * 8;
  }

  float4 a0[4], a1[4];
  // prologue: tile 0
#pragma unroll
  for (int it = 0; it < 4; ++it) {
    a0[it] = *reinterpret_cast<const float4*>(xg[it]);
    a1[it] = *reinterpret_cast<const float4*>(xg[it] + 4);
  }
#pragma unroll
  for (int it = 0; it < 2; ++it) gload_lds16(bgp[it], &Bl[0][(it * 256 + tid) * 8]);
  asm volatile("s_waitcnt vmcnt(2)" ::: "memory");  // A f32 regs landed (B still flying)
#pragma unroll
  for (int it = 0; it < 4; ++it) {
    u32x4 pk = {cvtpk(a0[it].x, a0[it].y), cvtpk(a0[it].z, a0[it].w),
                cvtpk(a1[it].x, a1[it].y), cvtpk(a1[it].z, a1[it].w)};
    *reinterpret_cast<u32x4*>(&Al[0][(it * 256 + tid) * 8]) = pk;
  }
  asm volatile("s_waitcnt lgkmcnt(0)" ::: "memory");

  int cur = 0;
  for (int t = 0; t < 8; ++t) {
    const int k0 = t * 64;
    if (t < 7) {
#pragma unroll
      for (int it = 0; it < 4; ++it) {
        a0[it] = *reinterpret_cast<const float4*>(xg[it] + k0 + 64);
        a1[it] = *reinterpret_cast<const float4*>(xg[it] + k0 + 68);
      }
#pragma unroll
      for (int it = 0; it < 2; ++it)
        gload_lds16(bgp[it] + k0 + 64, &Bl[cur ^ 1][(it * 256 + tid) * 8]);
      asm volatile("s_waitcnt vmcnt(10)" ::: "memory");  // B(t) done; 8 A + 2 B in flight
    } else {
      asm volatile("s_waitcnt vmcnt(0)" ::: "memory");
    }
    barrier_raw();
#pragma unroll
    for (int ks = 0; ks < 2; ++ks) {
      bf16x8 af[4], bf[2];
#pragma unroll
      for (int mf = 0; mf < 4; ++mf)
        af[mf] = *reinterpret_cast<const bf16x8*>(
            &Al[cur][(wr + mf * 16 + i) * 64 + ks * 32 + 8 * g]);
#pragma unroll
      for (int nf = 0; nf < 2; ++nf)
        bf[nf] = *reinterpret_cast<const bf16x8*>(
            &Bl[cur][(wc + nf * 16 + i) * 64 + ks * 32 + 8 * g]);
#pragma unroll
      for (int mf = 0; mf < 4; ++mf)
#pragma unroll
        for (int nf = 0; nf < 2; ++nf) acc[mf][nf] = mfma16(af[mf], bf[nf], acc[mf][nf]);
    }
    if (t < 7) {
      asm volatile("s_waitcnt vmcnt(2)" ::: "memory");  // A(t+1) regs landed
#pragma unroll
      for (int it = 0; it < 4; ++it) {
        u32x4 pk = {cvtpk(a0[it].x, a0[it].y), cvtpk(a0[it].z, a0[it].w),
                    cvtpk(a1[it].x, a1[it].y), cvtpk(a1[it].z, a1[it].w)};
        *reinterpret_cast<u32x4*>(&Al[cur ^ 1][(it * 256 + tid) * 8]) = pk;
      }
      asm volatile("s_waitcnt lgkmcnt(0)" ::: "memory");
    }
    barrier_raw();
    cur ^= 1;
  }

  if (n0 < 1024) {
    // Q/K region: store to compact QK [4096][1024]
#pragma unroll
    for (int nf = 0; nf < 2; ++nf) {
      const int col = n0 + wc + nf * 16 + i;
      const float bb = bias[col];
#pragma unroll
      for (int mf = 0; mf < 4; ++mf) {
#pragma unroll
        for (int r = 0; r < 4; ++r) {
          const int row = m0 + wr + mf * 16 + 4 * g + r;
          QK[(size_t)row * 1024 + col] = f2bf(acc[mf][nf][r] + bb);
        }
      }
    }
  } else {
    // V region: store transposed Vt[b*512 + vcol][seq]; 4 consecutive seq per frag
    const int b = m0 >> 10;
    const int s0b = (m0 & 1023) + wr;
#pragma unroll
    for (int nf = 0; nf < 2; ++nf) {
      const int col = n0 + wc + nf * 16 + i;
      const float bb = bias[col];
      const int vcol = col - 1024;
#pragma unroll
      for (int mf = 0; mf < 4; ++mf) {
        u16 pk[4];
#pragma unroll
        for (int r = 0; r < 4; ++r) pk[r] = f2bf(acc[mf][nf][r] + bb);
        const int ss = s0b + mf * 16 + 4 * g;
        *reinterpret_cast<uint2*>(&Vt[(size_t)(b * 512 + vcol) * 1024 + ss]) =
            *reinterpret_cast<const uint2*>(pk);
      }
    }
  }
}

// ------- out projection, 64x64 tile, dbuf + counted vmcnt: out = Cc @ BTo^T + bo -------
// grid (8, 64); 4 waves 2x2; wave 32x32 = 2x2 frags. BK=64.
__global__ __launch_bounds__(256) void gemm_out_kernel(const u16* __restrict__ A,
                                                       const u16* __restrict__ BT,
                                                       const float* __restrict__ bias,
                                                       float* __restrict__ Cf) {
  __shared__ __align__(16) u16 Al[2][64 * 64];
  __shared__ __align__(16) u16 Bl[2][64 * 64];
  const int K = 512;
  const int tid = threadIdx.x;
  const int w = tid >> 6, lane = tid & 63, g = lane >> 4, i = lane & 15;
  const int m0 = blockIdx.y * 64, n0 = blockIdx.x * 64;
  const int wr = (w >> 1) * 32, wc = (w & 1) * 32;

  f32x4 acc[2][2];
#pragma unroll
  for (int a = 0; a < 2; ++a)
#pragma unroll
    for (int b = 0; b < 2; ++b) acc[a][b] = f32x4{0.f, 0.f, 0.f, 0.f};

  const u16* agp[2];
  const u16* bgp[2];
#pragma unroll
  for (int it = 0; it < 2; ++it) {
    const int slot = it * 256 + tid;
    agp[it] = A + (size_t)(m0 + (slot >> 3)) * K + (slot & 7) * 8;
    bgp[it] = BT + (size_t)(n0 + (slot >> 3)) * K + (slot & 7) * 8;
  }

#define OSTAGE(bi, k0)                                              \
  do {                                                              \
    _Pragma("unroll") for (int it = 0; it < 2; ++it) {              \
      gload_lds16(agp[it] + (k0), &Al[bi][(it * 256 + tid) * 8]);   \
      gload_lds16(bgp[it] + (k0), &Bl[bi][(it * 256 + tid) * 8]);   \
    }                                                               \
  } while (0)

  OSTAGE(0, 0);
  int cur = 0;
  for (int t = 0; t < 8; ++t) {
    if (t < 7) {
      OSTAGE(cur ^ 1, t * 64 + 64);
      asm volatile("s_waitcnt vmcnt(4)" ::: "memory");
    } else {
      asm volatile("s_waitcnt vmcnt(0)" ::: "memory");
    }
    barrier_raw();
#pragma unroll
    for (int ks = 0; ks < 2; ++ks) {
      bf16x8 af[2], bf[2];
#pragma unroll
      for (int mf = 0; mf < 2; ++mf)
        af[mf] = *reinterpret_cast<const bf16x8*>(
            &Al[cur][(wr + mf * 16 + i) * 64 + ks * 32 + 8 * g]);
#pragma unroll
      for (int nf = 0; nf < 2; ++nf)
        bf[nf] = *reinterpret_cast<const bf16x8*>(
            &Bl[cur][(wc + nf * 16 + i) * 64 + ks * 32 + 8 * g]);
#pragma unroll
      for (int mf = 0; mf < 2; ++mf)
#pragma unroll
        for (int nf = 0; nf < 2; ++nf) acc[mf][nf] = mfma16(af[mf], bf[nf], acc[mf][nf]);
    }
    barrier_raw();
    cur ^= 1;
  }
#undef OSTAGE

#pragma unroll
  for (int nf = 0; nf < 2; ++nf) {
    const int col = n0 + wc + nf * 16 + i;
    const float bb = bias[col];
#pragma unroll
    for (int mf = 0; mf < 2; ++mf) {
#pragma unroll
      for (int r = 0; r < 4; ++r) {
        const int row = m0 + wr + mf * 16 + 4 * g + r;
        Cf[(size_t)row * 512 + col] = acc[mf][nf][r] + bb;
      }
    }
  }
}

// ---------------- attention: 32x32 swapped-QK, 4-way KV split ----------------
// grid (h=8, qt=8, b*4+s=16); 256 thr = 4 waves, wave w owns q rows [q0w, q0w+32)
// QK layout: [4096][1024] (Q at col h*64, K at col 512+h*64)
__global__ __launch_bounds__(256) void attn3_kernel(const u16* __restrict__ QK,
                                                    const u16* __restrict__ Vt,
                                                    u16* __restrict__ Opart16,
                                                    float* __restrict__ mlpart) {
  __shared__ __align__(16) u16 Kl[2][4096];  // [64 j][8 eb-blocks of 8] XOR-swizzled
  __shared__ __align__(16) u16 Vl[2][4096];  // [64 e][8 jb-blocks of 8] XOR-swizzled

  const int tid = threadIdx.x;
  const int w = tid >> 6, lane = tid & 63;
  const int col = lane & 31, hi = lane >> 5;
  const int h = blockIdx.x;  // XCD = flat%8 = h: per-XCD K/V locality
  const int zz = blockIdx.z;
  const int b = zz >> 2, s = zz & 3;
  const int bh = b * 8 + h;
  const int q0w = blockIdx.y * 128 + w * 32;
  const int kvlo = s * 256;
  const int hm = (h < 4) ? h : 4;
  const int band = 1 << hm;
  const int modm = (2 << hm) - 1;
  const int qrow = q0w + col;

  // Q fragments (B-operand): lane holds Q[qrow][16*et + 8*hi + b]
  bf16x8 qf[4];
  const size_t qoff = (size_t)(b * 1024 + qrow) * 1024 + h * 64 + 8 * hi;
#pragma unroll
  for (int et = 0; et < 4; ++et)
    qf[et] = *reinterpret_cast<const bf16x8*>(QK + qoff + 16 * et);

  // dilation bias per C-reg r (invariant across kv tiles: 64 % 2^(hm+1) == 0)
  float bias[16];
#pragma unroll
  for (int r = 0; r < 16; ++r) {
    int c = (r & 3) + 8 * (r >> 2) + 4 * hi;
    bias[r] = (((qrow - c) & modm) == 0) ? 0.f : -1e30f;
  }

  f32x16 accO0 = {}, accO1 = {};
  float m_run = -1e30f, l_run = 0.f;

  // staging: slot -> linear LDS (slot*16B); global source pre-swizzled (rule #21)
  const int slot0 = tid, slot1 = tid + 256;
  const int kj0 = slot0 >> 3, keb0 = (slot0 & 7) ^ (kj0 & 7);
  const int kj1 = slot1 >> 3, keb1 = (slot1 & 7) ^ (kj1 & 7);
  const u16* kg0 = QK + (size_t)(b * 1024 + kj0) * 1024 + 512 + h * 64 + keb0 * 8;
  const u16* kg1 = QK + (size_t)(b * 1024 + kj1) * 1024 + 512 + h * 64 + keb1 * 8;
  const u16* vg0 = Vt + (size_t)(bh * 64 + kj0) * 1024 + keb0 * 8;  // e=kj0, jb=keb0
  const u16* vg1 = Vt + (size_t)(bh * 64 + kj1) * 1024 + keb1 * 8;

#define STAGE(bi, kv0)                                                  \
  do {                                                                  \
    gload_lds16(kg0 + (size_t)(kv0) * 1024, &Kl[bi][slot0 * 8]);        \
    gload_lds16(kg1 + (size_t)(kv0) * 1024, &Kl[bi][slot1 * 8]);        \
    gload_lds16(vg0 + (kv0), &Vl[bi][slot0 * 8]);                       \
    gload_lds16(vg1 + (kv0), &Vl[bi][slot1 * 8]);                       \
  } while (0)

  STAGE(0, kvlo);
  int buf = 0;

  for (int t = 0; t < 4; ++t) {
    const int kv0 = kvlo + t * 64;
    if (t < 3) {
      STAGE(buf ^ 1, kv0 + 64);
      asm volatile("s_waitcnt vmcnt(4)" ::: "memory");
    } else {
      asm volatile("s_waitcnt vmcnt(0)" ::: "memory");
    }
    barrier_raw();

    const u16* Kb = Kl[buf];
    const u16* Vb = Vl[buf];

    // QK^T swapped: s = mfma(K, Q); D[m=j][n=q], lane: n=col, m=crow(r,hi)
    f32x16 s0 = {}, s1 = {};
    __builtin_amdgcn_s_setprio(1);
#pragma unroll
    for (int et = 0; et < 4; ++et) {
      const int sw = ((2 * et + hi) ^ (col & 7)) << 3;
      bf16x8 kf0 = *reinterpret_cast<const bf16x8*>(&Kb[col * 64 + sw]);
      bf16x8 kf1 = *reinterpret_cast<const bf16x8*>(&Kb[(col + 32) * 64 + sw]);
      s0 = mfma32(kf0, qf[et], s0);
      s1 = mfma32(kf1, qf[et], s1);
    }
    __builtin_amdgcn_s_setprio(0);

    // mask (scores already in exp2 domain)
    float p[32];
    const int dq = qrow - kv0;
    const bool near = (q0w <= kv0 + 63 + band) && (kv0 <= q0w + 31 + band);
    if (near) {
#pragma unroll
      for (int r = 0; r < 16; ++r) {
        const int c = (r & 3) + 8 * (r >> 2) + 4 * hi;
        int d0 = dq - c, d1 = d0 - 32;
        d0 = d0 < 0 ? -d0 : d0;
        d1 = d1 < 0 ? -d1 : d1;
        p[r] = (d0 <= band) ? s0[r] : s0[r] + bias[r];
        p[r + 16] = (d1 <= band) ? s1[r] : s1[r] + bias[r];
      }
    } else {
#pragma unroll
      for (int r = 0; r < 16; ++r) {
        p[r] = s0[r] + bias[r];
        p[r + 16] = s1[r] + bias[r];
      }
    }

    // row max: tree reduce (5 dep levels) + lane^32 combine
    float tr[16];
#pragma unroll
    for (int j = 0; j < 16; ++j) tr[j] = fmaxf(p[j], p[j + 16]);
#pragma unroll
    for (int st = 8; st >= 1; st >>= 1)
#pragma unroll
      for (int j = 0; j < st; ++j) tr[j] = fmaxf(tr[j], tr[j + st]);
    float mu = fmaxf(tr[0], __shfl_xor(tr[0], 32));

    // defer-max (T13): rescale only on real growth
    if (__any(mu > m_run + 8.f)) {
      float mn = fmaxf(m_run, mu);
      float corr = EXP2F(m_run - mn);
      m_run = mn;
      l_run *= corr;
#pragma unroll
      for (int j = 0; j < 16; ++j) {
        accO0[j] *= corr;
        accO1[j] *= corr;
      }
    }

#pragma unroll
    for (int j = 0; j < 32; ++j) p[j] = EXP2F(p[j] - m_run);
    float ts[16];
#pragma unroll
    for (int j = 0; j < 16; ++j) ts[j] = p[j] + p[j + 16];
#pragma unroll
    for (int st = 8; st >= 1; st >>= 1)
#pragma unroll
      for (int j = 0; j < st; ++j) ts[j] += ts[j + st];
    l_run += ts[0] + __shfl_xor(ts[0], 32);

    // P -> A-frag in-register (cvt_pk + shfl_xor lane^32 exchange), then PV
#pragma unroll
    for (int kt = 0; kt < 4; ++kt) {
      const float* pp = (kt < 2) ? p : p + 16;  // mt = kt>>1 (compile-time)
      const int R = (kt & 1) * 8;
      u32 A0 = cvtpk(pp[R + 0], pp[R + 1]);
      u32 A1 = cvtpk(pp[R + 2], pp[R + 3]);
      u32 B0 = cvtpk(pp[R + 4], pp[R + 5]);
      u32 B1 = cvtpk(pp[R + 6], pp[R + 7]);
      u32 xA0 = __shfl_xor(A0, 32), xA1 = __shfl_xor(A1, 32);
      u32 xB0 = __shfl_xor(B0, 32), xB1 = __shfl_xor(B1, 32);
      u32 w0 = hi ? xB0 : A0;
      u32 w1 = hi ? xB1 : A1;
      u32 w2 = hi ? B0 : xA0;
      u32 w3 = hi ? B1 : xA1;
      u32x4 pu = {w0, w1, w2, w3};
      bf16x8 paf = __builtin_bit_cast(bf16x8, pu);
      const int jb = 2 * kt + hi;
      __builtin_amdgcn_s_setprio(1);
      {
        const int erow = col;  // nt = 0
        bf16x8 vf = *reinterpret_cast<const bf16x8*>(&Vb[erow * 64 + ((jb ^ (erow & 7)) << 3)]);
        accO0 = mfma32(paf, vf, accO0);
      }
      {
        const int erow = 32 + col;  // nt = 1
        bf16x8 vf = *reinterpret_cast<const bf16x8*>(&Vb[erow * 64 + ((jb ^ (erow & 7)) << 3)]);
        accO1 = mfma32(paf, vf, accO1);
      }
      __builtin_amdgcn_s_setprio(0);
    }

    barrier_raw();
    buf ^= 1;
  }
#undef STAGE

  // epilogue: write unnormalized partial O (bf16) + per-row (m,l) f32
  const size_t obase = (size_t)(s * 32 + bh) * 1024 + q0w;
  if (lane < 32) {
    float2 ml2 = {m_run, l_run};
    *reinterpret_cast<float2*>(&mlpart[(obase + col) * 2]) = ml2;
  }
#pragma unroll
  for (int r = 0; r < 16; ++r) {
    const int c = (r & 3) + 8 * (r >> 2) + 4 * hi;
    u16* orow = Opart16 + (obase + c) * 64;
    orow[col] = f2bf(accO0[r]);
    orow[32 + col] = f2bf(accO1[r]);
  }
}

// ---------------- combine: merge 4 KV-split partials, write bf16 concat ----------------
__global__ __launch_bounds__(256) void attn_combine_kernel(const u16* __restrict__ Opart16,
                                                           const float* __restrict__ mlpart,
                                                           u16* __restrict__ Cc) {
  const int gid = blockIdx.x * 256 + threadIdx.x;  // 32768 rows * 16 e-quads
  const int rg = gid >> 4;                         // bh*1024 + qrow
  const int e0 = (gid & 15) * 4;
  float m[4], l[4];
#pragma unroll
  for (int s2 = 0; s2 < 4; ++s2) {
    float2 ml2 = *reinterpret_cast<const float2*>(&mlpart[((size_t)s2 * 32768 + rg) * 2]);
    m[s2] = ml2.x;
    l[s2] = ml2.y;
  }
  const float M = fmaxf(fmaxf(m[0], m[1]), fmaxf(m[2], m[3]));
  float L = 0.f, wsc[4];
#pragma unroll
  for (int s2 = 0; s2 < 4; ++s2) {
    wsc[s2] = EXP2F(m[s2] - M);
    L += l[s2] * wsc[s2];
  }
  float o0 = 0.f, o1 = 0.f, o2 = 0.f, o3 = 0.f;
#pragma unroll
  for (int s2 = 0; s2 < 4; ++s2) {
    uint2 raw =
        *reinterpret_cast<const uint2*>(&Opart16[((size_t)s2 * 32768 + rg) * 64 + e0]);
    o0 += bf2f((u16)(raw.x & 0xffff)) * wsc[s2];
    o1 += bf2f((u16)(raw.x >> 16)) * wsc[s2];
    o2 += bf2f((u16)(raw.y & 0xffff)) * wsc[s2];
    o3 += bf2f((u16)(raw.y >> 16)) * wsc[s2];
  }
  const float inv = 1.0f / L;
  const int bh = rg >> 10, qr = rg & 1023;
  u16 ob[4] = {f2bf(o0 * inv), f2bf(o1 * inv), f2bf(o2 * inv), f2bf(o3 * inv)};
  *reinterpret_cast<uint2*>(&Cc[(size_t)((bh >> 3) * 1024 + qr) * 512 + (bh & 7) * 64 + e0]) =
      *reinterpret_cast<const uint2*>(ob);
}

// ---------------- launch ----------------
extern "C" void kernel_launch(void* const* d_in, const int* in_sizes, int n_in,
                              void* d_out, int out_size, void* d_ws, size_t ws_size,
                              hipStream_t stream) {
  const float* x = (const float*)d_in[0];
  const float* Wq = (const float*)d_in[1];
  const float* bq = (const float*)d_in[2];
  const float* Wk = (const float*)d_in[3];
  const float* bk = (const float*)d_in[4];
  const float* Wv = (const float*)d_in[5];
  const float* bv = (const float*)d_in[6];
  const float* Wo = (const float*)d_in[7];
  const float* bo = (const float*)d_in[8];
  float* out = (float*)d_out;

  char* ws = (char*)d_ws;
  u16* BTqkv = (u16*)(ws + (4u << 20));     // 1.5 MB [1536][512]
  u16* BTo = (u16*)(ws + (6u << 20));       // 0.5 MB [512][512]
  float* bqkv = (float*)(ws + (7u << 20));  // 6 KB
  u16* QK = (u16*)(ws + (8u << 20));        // 8 MB   [4096][1024] (Q | K)
  u16* Cc = (u16*)(ws + (17u << 20));       // 4 MB   [4096][512]
  u16* Vt = (u16*)(ws + (21u << 20));       // 4 MB   [32*64][1024]
  u16* Opart16 = (u16*)(ws + (32u << 20));  // 16 MB  [4 splits][32 bh][1024][64] bf16
  float* mlpart = (float*)(ws + (64u << 20));  // 1 MB [4 splits][32 bh][1024][2]

  const int NW = 1536 * 512 + 512 * 512 + 1536;
  pack_w_kernel<<<(NW + 255) / 256, 256, 0, stream>>>(Wq, Wk, Wv, Wo, bq, bk, bv, BTqkv,
                                                      BTo, bqkv);

  // QKV projection (f32 A-pack fused, V transposed in epilogue): grid 24x32 (3/CU)
  gemm_qkv_kernel<<<dim3(24, 32), 256, 0, stream>>>(x, BTqkv, bqkv, QK, Vt);

  // attention: 4-way KV split (grid x=h for XCD L2 locality)
  attn3_kernel<<<dim3(8, 8, 16), 256, 0, stream>>>(QK, Vt, Opart16, mlpart);
  attn_combine_kernel<<<2048, 256, 0, stream>>>(Opart16, mlpart, Cc);

  // output projection: 64x64 tiles, grid 8x64 = 512 blocks (2/CU)
  gemm_out_kernel<<<dim3(8, 64), 256, 0, stream>>>(Cc, BTo, bo, out);
}